// Round 3
// baseline (836.287 us; speedup 1.0000x reference)
//
#include <hip/hip_runtime.h>
#include <hip/hip_bf16.h>
#include <math.h>

// B=8 C=32 P=128 D=256 H=8 R=32; time: 256 seqs x 128; chan: 1024 seqs x 32.
// Both paths: 32768 rows x 256. d_out FP32 (2 x 8,388,608). ws >= 166 MiB.
// g1/g2 bf16-packed in place into the quR plane (lo=g1, hi=g2 ushort halves).
// v7: outgemm moved to MFMA (bf16 A already; B split hi+lo bf16 => fp32-neutral),
//     G_t/G_c stores coalesced as uint4 (was 64 scattered 2B stores/thread).
#define LOG2T_16 0.8304820237218406f  // log2(10000)/16

typedef __attribute__((ext_vector_type(8))) short short8;
typedef __attribute__((ext_vector_type(4))) float f32x4;

#define PERM_LO 0x05040100u  // [x.b0,x.b1,y.b0,y.b1] from perm(y,x,sel)
#define PERM_HI 0x07060302u  // [x.b2,x.b3,y.b2,y.b3]

__device__ __forceinline__ float bf2f(unsigned short u) {
    union { float f; unsigned int i; } x; x.i = ((unsigned int)u) << 16; return x.f;
}
__device__ __forceinline__ unsigned short f2b(float f) {
    __hip_bfloat16 h = __float2bfloat16(f);
    union { __hip_bfloat16 h; unsigned short u; } x; x.h = h; return x.u;
}

__device__ __forceinline__ float v5_dot32(const float* qurow, const float* row) {
    float dot = 0.f;
#pragma unroll
    for (int q = 0; q < 8; q++) {
        float4 x = *(const float4*)(row + q * 4);
        dot = fmaf(qurow[q * 4 + 0], x.x, dot);
        dot = fmaf(qurow[q * 4 + 1], x.y, dot);
        dot = fmaf(qurow[q * 4 + 2], x.z, dot);
        dot = fmaf(qurow[q * 4 + 3], x.w, dot);
    }
    return dot;
}

__device__ __forceinline__ void v5_fma16(float p_, const float* row, int r0, float* acc) {
#pragma unroll
    for (int hh = 0; hh < 2; hh++) {
#pragma unroll
        for (int q = 0; q < 2; q++) {
            float4 x = *(const float4*)(row + r0 + hh * 16 + q * 4);
            float xs[4] = {x.x, x.y, x.z, x.w};
#pragma unroll
            for (int i = 0; i < 4; i++)
                acc[hh * 8 + q * 4 + i] = fmaf(p_, xs[i], acc[hh * 8 + q * 4 + i]);
        }
    }
}

__device__ __forceinline__ void v5_fma32(float p_, const float* row, float* acc) {
#pragma unroll
    for (int q = 0; q < 8; q++) {
        float4 x = *(const float4*)(row + q * 4);
        float xs[4] = {x.x, x.y, x.z, x.w};
#pragma unroll
        for (int i = 0; i < 4; i++)
            acc[q * 4 + i] = fmaf(p_, xs[i], acc[q * 4 + i]);
    }
}

// ---------- K0: prep B planes for MFMA outgemm: transpose u,v and split into
// packed bf16 hi|lo uints:  Bp[mtx][c][k] = bf16hi(u[k][c]) | bf16lo<<16 ----------
__global__ __launch_bounds__(256) void v7_prepB(
    const float* __restrict__ u_t, const float* __restrict__ v_t,
    const float* __restrict__ u_c, const float* __restrict__ v_c,
    unsigned int* __restrict__ Bp)
{
    __shared__ float Ts[64][65];
    const int mtx = blockIdx.y;
    const float* src = (mtx == 0) ? u_t : (mtx == 1) ? v_t : (mtx == 2) ? u_c : v_c;
    unsigned int* dst = Bp + (size_t)mtx * 65536;
    const int k0 = (blockIdx.x >> 2) * 64;
    const int c0 = (blockIdx.x & 3) * 64;
    const int tid = threadIdx.x;
    const int lr = tid >> 2;              // 0..63
    const int lc0 = (tid & 3) * 16;
#pragma unroll
    for (int q = 0; q < 4; q++) {
        float4 x = *(const float4*)(src + (size_t)(k0 + lr) * 256 + c0 + lc0 + q * 4);
        *(float4*)&Ts[lr][lc0 + q * 4] = x;     // Ts[k_local][c_local]
    }
    __syncthreads();
#pragma unroll
    for (int q = 0; q < 4; q++) {
        unsigned int w[4];
#pragma unroll
        for (int e = 0; e < 4; e++) {
            float x = Ts[lc0 + q * 4 + e][lr];
            unsigned short hi = f2b(x);
            unsigned short lo = f2b(x - bf2f(hi));
            w[e] = (unsigned int)hi | ((unsigned int)lo << 16);
        }
        *(uint4*)(dst + (size_t)(c0 + lr) * 256 + k0 + lc0 + q * 4) =
            make_uint4(w[0], w[1], w[2], w[3]);
    }
}

// ---------- K1: [qu_rot | qv_rot] = RoPE(qz @ [u;v]^T), 64x64 tiles (unchanged) ----------
__global__ __launch_bounds__(256) void v5_proj(
    const float* __restrict__ qz, const float* __restrict__ u, const float* __restrict__ v,
    float* __restrict__ qu_rot, float* __restrict__ qv_rot, int chan, int posmask)
{
    __shared__ float As[16][68];
    __shared__ float Bs[16][68];
    __shared__ float Ct[64][68];
    const int row0 = blockIdx.x * 64;
    const int col0 = blockIdx.y * 64;               // 0..511
    const float* Bsrc = (col0 < 256) ? (u + col0 * 256) : (v + (col0 - 256) * 256);
    float* Cout = (col0 < 256) ? qu_rot : qv_rot;
    const int ccol0 = col0 & 255;
    const int tid = threadIdx.x;

    const int am = tid >> 2;
    const int ak = (tid & 3) * 4;
    int arow = row0 + am;
    if (chan) {
        int b = arow >> 12, p = (arow >> 5) & 127, c = arow & 31;
        arow = (b * 32 + c) * 128 + p;
    }
    const float* aptr = qz + (size_t)arow * 256 + ak;
    const float* bptr = Bsrc + (size_t)am * 256 + ak;

    const int tm = tid >> 4, tn = tid & 15;
    float acc[4][4] = {};
    for (int k0 = 0; k0 < 256; k0 += 16) {
        float4 a4 = *(const float4*)(aptr + k0);
        float4 b4 = *(const float4*)(bptr + k0);
        As[ak + 0][am] = a4.x; As[ak + 1][am] = a4.y; As[ak + 2][am] = a4.z; As[ak + 3][am] = a4.w;
        Bs[ak + 0][am] = b4.x; Bs[ak + 1][am] = b4.y; Bs[ak + 2][am] = b4.z; Bs[ak + 3][am] = b4.w;
        __syncthreads();
#pragma unroll
        for (int kk = 0; kk < 16; kk++) {
            float4 av = *(const float4*)&As[kk][tm * 4];
            float4 bv = *(const float4*)&Bs[kk][tn * 4];
            float ar[4] = {av.x, av.y, av.z, av.w};
            float br[4] = {bv.x, bv.y, bv.z, bv.w};
#pragma unroll
            for (int i = 0; i < 4; i++)
#pragma unroll
                for (int j = 0; j < 4; j++)
                    acc[i][j] = fmaf(ar[i], br[j], acc[i][j]);
        }
        __syncthreads();
    }
#pragma unroll
    for (int i = 0; i < 4; i++)
        *(float4*)&Ct[tm * 4 + i][tn * 4] = make_float4(acc[i][0], acc[i][1], acc[i][2], acc[i][3]);
    __syncthreads();
    const int r_local = tid >> 2;
    const int fj = (tid & 3) * 8;
    const int m = row0 + r_local;
    const float pos = (float)(m & posmask);
#pragma unroll
    for (int qq = 0; qq < 2; qq++) {
        int fhp = fj + qq * 4;                      // 0..28 step 4
        int hl = fhp >> 4, j0 = fhp & 15;
        int cl = hl * 32 + j0;
        float4 a4 = *(const float4*)&Ct[r_local][cl];
        float4 b4 = *(const float4*)&Ct[r_local][cl + 16];
        float aa[4] = {a4.x, a4.y, a4.z, a4.w};
        float bb[4] = {b4.x, b4.y, b4.z, b4.w};
        float o1[4], o2[4];
#pragma unroll
        for (int i = 0; i < 4; i++) {
            float ang = pos * exp2f(-(float)(j0 + i) * LOG2T_16);
            float sn, cs;
            sincosf(ang, &sn, &cs);                 // precise: pre-softmax path
            o1[i] = aa[i] * cs - bb[i] * sn;        // apply
            o2[i] = bb[i] * cs + aa[i] * sn;
        }
        *(float4*)(Cout + (size_t)m * 256 + ccol0 + cl)      = make_float4(o1[0], o1[1], o1[2], o1[3]);
        *(float4*)(Cout + (size_t)m * 256 + ccol0 + cl + 16) = make_float4(o2[0], o2[1], o2[2], o2[3]);
    }
}

// ---------- K2: time-path partial softmax stats (unchanged) ----------
__global__ __launch_bounds__(256) void v5_stats_t(
    const float* __restrict__ quR, const float* __restrict__ qvR,
    const float* __restrict__ mask, float* __restrict__ omax, float* __restrict__ osum)
{
    __shared__ float Qv[128][36];
    const int bid = blockIdx.x;                 // n*8 + h
    const int n = bid >> 3, h = bid & 7;
    const int b = n >> 5, c = n & 31;
    const int tid = threadIdx.x;
    for (int idx = tid * 4; idx < 4096; idx += 1024) {
        int s = idx >> 5, r = idx & 31;
        *(float4*)&Qv[s][r] = *(const float4*)(qvR + ((size_t)(n * 128 + s)) * 256 + h * 32 + r);
    }
    const int s = tid >> 1, toff = (tid & 1) * 64;
    float qurow[32];
    const float* qptr = quR + ((size_t)(n * 128 + s)) * 256 + h * 32;
#pragma unroll
    for (int q = 0; q < 8; q++) {
        float4 x = *(const float4*)(qptr + q * 4);
        qurow[q * 4 + 0] = x.x; qurow[q * 4 + 1] = x.y; qurow[q * 4 + 2] = x.z; qurow[q * 4 + 3] = x.w;
    }
    __syncthreads();
    const float* mrow = mask + (size_t)n * 16384 + s * 128 + toff;
    float mx = -1e30f, sm = 0.f;
#pragma unroll 4
    for (int t = 0; t < 64; t++) {
        float dot = v5_dot32(qurow, &Qv[toff + t][0]);
        float vv = 256.f * (dot + mrow[t]);
        float nm = fmaxf(mx, vv);
        sm = sm * __expf(mx - nm) + __expf(vv - nm);
        mx = nm;
    }
    float omx = __shfl_xor(mx, 1);
    float osm = __shfl_xor(sm, 1);
    float fm = fmaxf(mx, omx);
    float fs = sm * __expf(mx - fm) + osm * __expf(omx - fm);
    if ((tid & 1) == 0) {
        int idx = ((b * 8 + h) * 32 + c) * 128 + s;
        omax[idx] = fm; osum[idx] = fs;
    }
}

// ---------- K3: chan-path partial softmax stats (unchanged) ----------
__global__ __launch_bounds__(256) void v5_stats_c(
    const float* __restrict__ quR, const float* __restrict__ qvR,
    const float* __restrict__ mask, float* __restrict__ omax, float* __restrict__ osum)
{
    __shared__ float Qv[32][260];
    const int m = blockIdx.x;                   // b*128 + p
    const int b = m >> 7, p = m & 127;
    const int tid = threadIdx.x;
    for (int idx = tid * 4; idx < 8192; idx += 1024) {
        int sc = idx >> 8, dd = idx & 255;
        *(float4*)&Qv[sc][dd] = *(const float4*)(qvR + ((size_t)m * 32 + sc) * 256 + dd);
    }
    const int h = tid >> 5, sc = tid & 31;
    float qurow[32];
    const float* qptr = quR + ((size_t)m * 32 + sc) * 256 + h * 32;
#pragma unroll
    for (int q = 0; q < 8; q++) {
        float4 x = *(const float4*)(qptr + q * 4);
        qurow[q * 4 + 0] = x.x; qurow[q * 4 + 1] = x.y; qurow[q * 4 + 2] = x.z; qurow[q * 4 + 3] = x.w;
    }
    __syncthreads();
    const float* mrow = mask + (size_t)m * 1024 + sc * 32;
    float mx = -1e30f, sm = 0.f;
#pragma unroll 4
    for (int t = 0; t < 32; t++) {
        float dot = v5_dot32(qurow, &Qv[t][h * 32]);
        float vv = 256.f * (dot + mrow[t]);
        float nm = fmaxf(mx, vv);
        sm = sm * __expf(mx - nm) + __expf(vv - nm);
        mx = nm;
    }
    int idx = ((b * 8 + h) * 32 + sc) * 128 + p;
    omax[idx] = mx; osum[idx] = sm;
}

// ---------- K4: merge joint-softmax stats (unchanged) ----------
__global__ __launch_bounds__(256) void v5_merge(
    const float* __restrict__ mt, const float* __restrict__ st,
    const float* __restrict__ mc, const float* __restrict__ sc,
    float* __restrict__ Mo, float* __restrict__ So)
{
    int i = blockIdx.x * 256 + threadIdx.x;
    float a = mt[i], b = mc[i];
    float mx = fmaxf(a, b);
    float s = st[i] * __expf(a - mx) + sc[i] * __expf(b - mx);
    Mo[i] = mx;
    So[i] = 1.f / s;
}

// ---------- K5 v7: time-path G. Same math as v6; g1 held packed in regs and the
// final store is 4x uint4 per thread (was 64 scattered 2B stores). ----------
__global__ __launch_bounds__(256) void v6_G_t(
    const float* quR, const float* qvR,
    const float* __restrict__ mask, const float* __restrict__ Mr, const float* __restrict__ Sv,
    unsigned int* gpk)
{
    __shared__ float Qv[128][36];
    __shared__ unsigned short Pm[128][132];
    const int bid = blockIdx.x;
    const int n = bid >> 3, h = bid & 7;
    const int b = n >> 5, c = n & 31;
    const int tid = threadIdx.x;
    for (int idx = tid * 4; idx < 4096; idx += 1024) {
        int s = idx >> 5, r = idx & 31;
        *(float4*)&Qv[s][r] = *(const float4*)(qvR + ((size_t)(n * 128 + s)) * 256 + h * 32 + r);
    }
    const int s = tid >> 1;
    const int half = tid & 1;
    const int toff = half * 64;
    const int r0 = half * 8;
    {
        float qurow[32];
        const float* qptr = quR + ((size_t)(n * 128 + s)) * 256 + h * 32;
#pragma unroll
        for (int q = 0; q < 8; q++) {
            float4 x = *(const float4*)(qptr + q * 4);
            qurow[q * 4 + 0] = x.x; qurow[q * 4 + 1] = x.y; qurow[q * 4 + 2] = x.z; qurow[q * 4 + 3] = x.w;
        }
        __syncthreads();
        const int rowidx = ((b * 8 + h) * 32 + c) * 128 + s;
        const float Mx = Mr[rowidx];
        const float Si = Sv[rowidx];
        const float* mrow = mask + (size_t)n * 16384 + s * 128 + toff;
#pragma unroll 4
        for (int t = 0; t < 64; t++) {
            float dot = v5_dot32(qurow, &Qv[toff + t][0]);
            float pv = __expf(256.f * (dot + mrow[t]) - Mx) * Si;
            Pm[s][toff + t] = f2b(pv);
        }
    }
    __syncthreads();
    // g1[s][r] = sum_t P[s][t] * Qv[t][r]
    float acc[16] = {};
#pragma unroll 8
    for (int t = 0; t < 128; t++) {
        float p_ = bf2f(Pm[s][t]);
        v5_fma16(p_, &Qv[t][0], r0, acc);
    }
    // rotation angles (register-only; needed for g1 pack now and g2 later)
    float cs[8], sn[8];
#pragma unroll
    for (int i = 0; i < 8; i++) {
        float ang = (float)s * exp2f(-(float)(r0 + i) * LOG2T_16);
        __sincosf(ang, &sn[i], &cs[i]);
    }
    // pack rotated g1 (apply_o, pos=s) into 8 uints: cols r0..r0+7 / r0+16..+23
    unsigned int g1p[4], g1q[4];
#pragma unroll
    for (int j = 0; j < 4; j++) {
        int i0 = 2 * j, i1 = 2 * j + 1;
        float x0 = acc[i0], y0 = acc[8 + i0], x1 = acc[i1], y1 = acc[8 + i1];
        g1p[j] = (unsigned int)f2b(x0 * cs[i0] + y0 * sn[i0])
               | ((unsigned int)f2b(x1 * cs[i1] + y1 * sn[i1]) << 16);
        g1q[j] = (unsigned int)f2b(y0 * cs[i0] - x0 * sn[i0])
               | ((unsigned int)f2b(y1 * cs[i1] - x1 * sn[i1]) << 16);
    }
    __syncthreads();                              // all g1 Qv reads done
    // restage Qo = R(-2theta)*quR into Qv (LAST quR reads, before any gpk write)
    for (int idx = tid * 4; idx < 2048; idx += 1024) {
        int row = idx >> 4, j0 = idx & 15;
        const float* base = quR + ((size_t)(n * 128 + row)) * 256 + h * 32;
        float4 a4 = *(const float4*)(base + j0);
        float4 b4 = *(const float4*)(base + j0 + 16);
        float aa[4] = {a4.x, a4.y, a4.z, a4.w};
        float bb[4] = {b4.x, b4.y, b4.z, b4.w};
        float o1[4], o2[4];
#pragma unroll
        for (int i = 0; i < 4; i++) {
            float ang = 2.f * (float)row * exp2f(-(float)(j0 + i) * LOG2T_16);
            float s2, c2;
            __sincosf(ang, &s2, &c2);             // fast: post-softmax path
            o1[i] = aa[i] * c2 + bb[i] * s2;
            o2[i] = bb[i] * c2 - aa[i] * s2;
        }
        *(float4*)&Qv[row][j0]      = make_float4(o1[0], o1[1], o1[2], o1[3]);
        *(float4*)&Qv[row][j0 + 16] = make_float4(o2[0], o2[1], o2[2], o2[3]);
    }
    __syncthreads();
    // g2[s][r] = sum_t P[t][s] * Qo[t][r] — reuse acc
#pragma unroll
    for (int i = 0; i < 16; i++) acc[i] = 0.f;
#pragma unroll 8
    for (int t = 0; t < 128; t++) {
        float p_ = bf2f(Pm[t][s]);
        v5_fma16(p_, &Qv[t][0], r0, acc);
    }
    // combine g1 (lo) | g2 (hi, apply pos=s) and store coalesced uint4s
    unsigned int* gp = gpk + ((size_t)(n * 128 + s)) * 256 + h * 32;
    unsigned int wo[8];
#pragma unroll
    for (int j = 0; j < 4; j++) {
        int i0 = 2 * j, i1 = 2 * j + 1;
        wo[i0] = (g1p[j] & 0xffffu)
               | ((unsigned int)f2b(acc[i0] * cs[i0] - acc[8 + i0] * sn[i0]) << 16);
        wo[i1] = (g1p[j] >> 16)
               | ((unsigned int)f2b(acc[i1] * cs[i1] - acc[8 + i1] * sn[i1]) << 16);
    }
    *(uint4*)(gp + r0)     = make_uint4(wo[0], wo[1], wo[2], wo[3]);
    *(uint4*)(gp + r0 + 4) = make_uint4(wo[4], wo[5], wo[6], wo[7]);
#pragma unroll
    for (int j = 0; j < 4; j++) {
        int i0 = 2 * j, i1 = 2 * j + 1;
        wo[i0] = (g1q[j] & 0xffffu)
               | ((unsigned int)f2b(acc[8 + i0] * cs[i0] + acc[i0] * sn[i0]) << 16);
        wo[i1] = (g1q[j] >> 16)
               | ((unsigned int)f2b(acc[8 + i1] * cs[i1] + acc[i1] * sn[i1]) << 16);
    }
    *(uint4*)(gp + r0 + 16) = make_uint4(wo[0], wo[1], wo[2], wo[3]);
    *(uint4*)(gp + r0 + 20) = make_uint4(wo[4], wo[5], wo[6], wo[7]);
}

// ---------- K6 v7: chan-path G, register-lean + packed coalesced stores ----------
__global__ __launch_bounds__(256) void v6_G_c(
    const float* quR, const float* qvR,
    const float* __restrict__ mask, const float* __restrict__ Mr, const float* __restrict__ Sv,
    unsigned int* gpk)
{
    __shared__ float Qv[32][260];
    __shared__ unsigned short Pm[8][32][34];      // [h][cand][query]
    const int m = blockIdx.x;                     // b*128 + p
    const int b = m >> 7, p = m & 127;
    const int tid = threadIdx.x;
    for (int idx = tid * 4; idx < 8192; idx += 1024) {
        int sc = idx >> 8, dd = idx & 255;
        *(float4*)&Qv[sc][dd] = *(const float4*)(qvR + ((size_t)m * 32 + sc) * 256 + dd);
    }
    const int h = tid >> 5, sc = tid & 31;
    {
        float qurow[32];
        const float* qptr = quR + ((size_t)m * 32 + sc) * 256 + h * 32;
#pragma unroll
        for (int q = 0; q < 8; q++) {
            float4 x = *(const float4*)(qptr + q * 4);
            qurow[q * 4 + 0] = x.x; qurow[q * 4 + 1] = x.y; qurow[q * 4 + 2] = x.z; qurow[q * 4 + 3] = x.w;
        }
        __syncthreads();
        const int rowidx = ((b * 8 + h) * 32 + sc) * 128 + p;
        const float Mx = Mr[rowidx], Si = Sv[rowidx];
        const float* mrow = mask + (size_t)m * 1024 + sc * 32;
#pragma unroll 4
        for (int t = 0; t < 32; t++) {
            float dot = v5_dot32(qurow, &Qv[t][h * 32]);
            float pv = __expf(256.f * (dot + mrow[t]) - Mx) * Si;
            Pm[h][t][sc] = f2b(pv);               // no pv[32] register array
        }
    }
    __syncthreads();                              // Pm complete
    // g1[sc][r] = sum_t P[sc][t] * Qv[t][r]  (P re-read from LDS: own writes)
    float a[32] = {};
#pragma unroll 4
    for (int t = 0; t < 32; t++) {
        float p_ = bf2f(Pm[h][t][sc]);
        v5_fma32(p_, &Qv[t][h * 32], a);
    }
    float cs[16], sn[16];
#pragma unroll
    for (int i = 0; i < 16; i++) {
        float ang = (float)sc * exp2f(-(float)i * LOG2T_16);
        __sincosf(ang, &sn[i], &cs[i]);
    }
    // pack rotated g1 (apply_o, pos=sc): cols 0..15 (g1p) and 16..31 (g1q)
    unsigned int g1p[8], g1q[8];
#pragma unroll
    for (int j = 0; j < 8; j++) {
        int i0 = 2 * j, i1 = 2 * j + 1;
        float x0 = a[i0], y0 = a[16 + i0], x1 = a[i1], y1 = a[16 + i1];
        g1p[j] = (unsigned int)f2b(x0 * cs[i0] + y0 * sn[i0])
               | ((unsigned int)f2b(x1 * cs[i1] + y1 * sn[i1]) << 16);
        g1q[j] = (unsigned int)f2b(y0 * cs[i0] - x0 * sn[i0])
               | ((unsigned int)f2b(y1 * cs[i1] - x1 * sn[i1]) << 16);
    }
    __syncthreads();                              // g1 Qv reads done
    // restage Qo = R(-2theta)*quR into Qv (LAST quR reads, before gpk writes)
    for (int idx = tid * 4; idx < 4096; idx += 1024) {
        int row = idx >> 7, rem = idx & 127;
        int h2 = rem >> 4, j0 = rem & 15;
        const float* base = quR + ((size_t)m * 32 + row) * 256 + h2 * 32;
        float4 a4 = *(const float4*)(base + j0);
        float4 b4 = *(const float4*)(base + j0 + 16);
        float aa[4] = {a4.x, a4.y, a4.z, a4.w};
        float bb[4] = {b4.x, b4.y, b4.z, b4.w};
        float o1[4], o2[4];
#pragma unroll
        for (int i = 0; i < 4; i++) {
            float ang = 2.f * (float)row * exp2f(-(float)(j0 + i) * LOG2T_16);
            float s2, c2;
            __sincosf(ang, &s2, &c2);             // fast: post-softmax path
            o1[i] = aa[i] * c2 + bb[i] * s2;
            o2[i] = bb[i] * c2 - aa[i] * s2;
        }
        *(float4*)&Qv[row][h2 * 32 + j0]      = make_float4(o1[0], o1[1], o1[2], o1[3]);
        *(float4*)&Qv[row][h2 * 32 + j0 + 16] = make_float4(o2[0], o2[1], o2[2], o2[3]);
    }
    __syncthreads();
    // g2[sc][r] = sum_t P[t][sc] * Qo[t][r];  P[t][sc] = Pm[h][sc][t] — reuse a
#pragma unroll
    for (int i = 0; i < 32; i++) a[i] = 0.f;
#pragma unroll 4
    for (int t = 0; t < 32; t++) {
        float p_ = bf2f(Pm[h][sc][t]);
        v5_fma32(p_, &Qv[t][h * 32], a);
    }
    // combine g1 (lo) | g2 (hi, apply pos=sc), store 8x uint4 coalesced
    unsigned int* gp = gpk + ((size_t)m * 32 + sc) * 256 + h * 32;
    unsigned int wo[16];
#pragma unroll
    for (int j = 0; j < 8; j++) {
        int i0 = 2 * j, i1 = 2 * j + 1;
        wo[i0] = (g1p[j] & 0xffffu)
               | ((unsigned int)f2b(a[i0] * cs[i0] - a[16 + i0] * sn[i0]) << 16);
        wo[i1] = (g1p[j] >> 16)
               | ((unsigned int)f2b(a[i1] * cs[i1] - a[16 + i1] * sn[i1]) << 16);
    }
#pragma unroll
    for (int q = 0; q < 4; q++)
        *(uint4*)(gp + q * 4) = make_uint4(wo[q * 4], wo[q * 4 + 1], wo[q * 4 + 2], wo[q * 4 + 3]);
#pragma unroll
    for (int j = 0; j < 8; j++) {
        int i0 = 2 * j, i1 = 2 * j + 1;
        wo[i0] = (g1q[j] & 0xffffu)
               | ((unsigned int)f2b(a[16 + i0] * cs[i0] + a[i0] * sn[i0]) << 16);
        wo[i1] = (g1q[j] >> 16)
               | ((unsigned int)f2b(a[16 + i1] * cs[i1] + a[i1] * sn[i1]) << 16);
    }
#pragma unroll
    for (int q = 0; q < 4; q++)
        *(uint4*)(gp + 16 + q * 4) = make_uint4(wo[q * 4], wo[q * 4 + 1], wo[q * 4 + 2], wo[q * 4 + 3]);
}

// ---------- K7 v7: out = g1 @ u + g2 @ v via bf16 MFMA, split-B (u=u_hi+u_lo)
// for fp32-equivalent B precision. 128x128 tile, 4 waves (2x2), K-step 32. ----------
__global__ __launch_bounds__(256) void v7_outgemm(
    const unsigned int* __restrict__ gpk,   // [32768][256]: lo=g1 bf16, hi=g2 bf16
    const unsigned int* __restrict__ Bu,    // [256c][256k]: lo=bf16hi(u[k][c]), hi=bf16lo
    const unsigned int* __restrict__ Bv,
    float* __restrict__ out, int remap)
{
    // stride 40 ushorts = 80B: 16B-aligned rows, capacity-perfect bank spread
    __shared__ __align__(16) unsigned short A1[128][40];     // g1
    __shared__ __align__(16) unsigned short A2[128][40];     // g2
    __shared__ __align__(16) unsigned short Bh[2][128][40];  // {u,v} hi-part
    __shared__ __align__(16) unsigned short Bl[2][128][40];  // {u,v} lo-part
    const int row0 = blockIdx.x * 128;
    const int col0 = blockIdx.y * 128;
    const int tid = threadIdx.x;
    const int sr = tid >> 1;                 // staging row/col 0..127
    const int sk = (tid & 1) * 16;           // staging k offset {0,16}
    const int wv = tid >> 6;
    const int lane = tid & 63;
    const int wr = (wv >> 1) * 64, wc = (wv & 1) * 64;
    const int fr = lane & 15;                // fragment row (A) / col (B)
    const int fk = (lane >> 4) * 8;          // fragment k offset {0,8,16,24}

    const unsigned int* aptr = gpk + (size_t)(row0 + sr) * 256 + sk;
    const unsigned int* uptr = Bu + (size_t)(col0 + sr) * 256 + sk;
    const unsigned int* vptr = Bv + (size_t)(col0 + sr) * 256 + sk;

    f32x4 acc[4][4] = {};

    for (int k0 = 0; k0 < 256; k0 += 32) {
#pragma unroll
        for (int q = 0; q < 4; q++) {
            uint4 wA = *(const uint4*)(aptr + k0 + q * 4);
            *(uint2*)&A1[sr][sk + q * 4] = make_uint2(
                __builtin_amdgcn_perm(wA.y, wA.x, PERM_LO),
                __builtin_amdgcn_perm(wA.w, wA.z, PERM_LO));
            *(uint2*)&A2[sr][sk + q * 4] = make_uint2(
                __builtin_amdgcn_perm(wA.y, wA.x, PERM_HI),
                __builtin_amdgcn_perm(wA.w, wA.z, PERM_HI));
            uint4 wU = *(const uint4*)(uptr + k0 + q * 4);
            *(uint2*)&Bh[0][sr][sk + q * 4] = make_uint2(
                __builtin_amdgcn_perm(wU.y, wU.x, PERM_LO),
                __builtin_amdgcn_perm(wU.w, wU.z, PERM_LO));
            *(uint2*)&Bl[0][sr][sk + q * 4] = make_uint2(
                __builtin_amdgcn_perm(wU.y, wU.x, PERM_HI),
                __builtin_amdgcn_perm(wU.w, wU.z, PERM_HI));
            uint4 wV = *(const uint4*)(vptr + k0 + q * 4);
            *(uint2*)&Bh[1][sr][sk + q * 4] = make_uint2(
                __builtin_amdgcn_perm(wV.y, wV.x, PERM_LO),
                __builtin_amdgcn_perm(wV.w, wV.z, PERM_LO));
            *(uint2*)&Bl[1][sr][sk + q * 4] = make_uint2(
                __builtin_amdgcn_perm(wV.y, wV.x, PERM_HI),
                __builtin_amdgcn_perm(wV.w, wV.z, PERM_HI));
        }
        __syncthreads();
        short8 a1[4], a2[4];
#pragma unroll
        for (int i = 0; i < 4; i++) {
            a1[i] = *(const short8*)&A1[wr + i * 16 + fr][fk];
            a2[i] = *(const short8*)&A2[wr + i * 16 + fr][fk];
        }
#pragma unroll
        for (int j = 0; j < 4; j++) {
            const int bc = wc + j * 16 + fr;
            short8 buh = *(const short8*)&Bh[0][bc][fk];
            short8 bul = *(const short8*)&Bl[0][bc][fk];
            short8 bvh = *(const short8*)&Bh[1][bc][fk];
            short8 bvl = *(const short8*)&Bl[1][bc][fk];
#pragma unroll
            for (int i = 0; i < 4; i++) {
                acc[i][j] = __builtin_amdgcn_mfma_f32_16x16x32_bf16(a1[i], buh, acc[i][j], 0, 0, 0);
                acc[i][j] = __builtin_amdgcn_mfma_f32_16x16x32_bf16(a1[i], bul, acc[i][j], 0, 0, 0);
                acc[i][j] = __builtin_amdgcn_mfma_f32_16x16x32_bf16(a2[i], bvh, acc[i][j], 0, 0, 0);
                acc[i][j] = __builtin_amdgcn_mfma_f32_16x16x32_bf16(a2[i], bvl, acc[i][j], 0, 0, 0);
            }
        }
        __syncthreads();
    }
    // epilogue: D frag (i,j): row = wr+i*16+(lane>>4)*4+r, col = wc+j*16+fr
#pragma unroll
    for (int i = 0; i < 4; i++) {
#pragma unroll
        for (int r = 0; r < 4; r++) {
            int mr = row0 + wr + i * 16 + (lane >> 4) * 4 + r;
            int orow = mr;
            if (remap) {                           // m=(b,p,c) -> (b,c,p)
                int bb = mr >> 12, pp = (mr >> 5) & 127, cc = mr & 31;
                orow = (bb << 12) + (cc << 7) + pp;
            }
            float* op = out + (size_t)orow * 256 + col0 + wc + fr;
#pragma unroll
            for (int j = 0; j < 4; j++)
                op[j * 16] = acc[i][j][r];
        }
    }
}

extern "C" void kernel_launch(void* const* d_in, const int* in_sizes, int n_in,
                              void* d_out, int out_size, void* d_ws, size_t ws_size,
                              hipStream_t stream)
{
    (void)in_sizes; (void)n_in; (void)out_size; (void)ws_size;
    const float* qz     = (const float*)d_in[0];
    const float* mask_t = (const float*)d_in[1];
    const float* mask_c = (const float*)d_in[2];
    const float* u_time = (const float*)d_in[3];
    const float* v_time = (const float*)d_in[4];
    const float* u_chan = (const float*)d_in[5];
    const float* v_chan = (const float*)d_in[6];
    float* out = (float*)d_out;                   // FP32 output (reference dtype)
    float* W = (float*)d_ws;

    // ws layout (floats): 4 planes + stats + packed-B planes = ~141 MiB total
    float* quR_t = W;                             // 8,388,608 each plane
    float* qvR_t = W + 8388608;
    float* quR_c = W + 16777216;
    float* qvR_c = W + 25165824;
    float* S     = W + 33554432;                  // stats: 6 x 262,144
    float* max_t = S;
    float* sum_t = S + 262144;
    float* max_c = S + 524288;
    float* sum_c = S + 786432;
    float* Mrow  = S + 1048576;
    float* Sinv  = S + 1310720;
    unsigned int* BP = (unsigned int*)(W + 35127296);   // 4 x 65,536 uints (1 MiB)
    unsigned int* GPt = (unsigned int*)quR_t;     // packed g1|g2 planes (alias)
    unsigned int* GPc = (unsigned int*)quR_c;

    dim3 blk(256);
    v7_prepB<<<dim3(16, 4), blk, 0, stream>>>(u_time, v_time, u_chan, v_chan, BP);
    v5_proj<<<dim3(512, 8), blk, 0, stream>>>(qz, u_time, v_time, quR_t, qvR_t, 0, 127);
    v5_proj<<<dim3(512, 8), blk, 0, stream>>>(qz, u_chan, v_chan, quR_c, qvR_c, 1, 31);
    v5_stats_t<<<2048, blk, 0, stream>>>(quR_t, qvR_t, mask_t, max_t, sum_t);
    v5_stats_c<<<1024, blk, 0, stream>>>(quR_c, qvR_c, mask_c, max_c, sum_c);
    v5_merge<<<1024, blk, 0, stream>>>(max_t, sum_t, max_c, sum_c, Mrow, Sinv);
    v6_G_t<<<2048, blk, 0, stream>>>(quR_t, qvR_t, mask_t, Mrow, Sinv, GPt);
    v7_outgemm<<<dim3(256, 2), blk, 0, stream>>>(GPt, BP, BP + 65536, out, 0);
    v6_G_c<<<1024, blk, 0, stream>>>(quR_c, qvR_c, mask_c, Mrow, Sinv, GPc);
    v7_outgemm<<<dim3(256, 2), blk, 0, stream>>>(GPc, BP + 131072, BP + 196608, out + 8388608, 1);
}

// Round 14
// 735.382 us; speedup vs baseline: 1.1372x; 1.1372x over previous
//
#include <hip/hip_runtime.h>
#include <hip/hip_bf16.h>
#include <math.h>

// B=8 C=32 P=128 D=256 H=8 R=32; time: 256 seqs x 128; chan: 1024 seqs x 32.
// v8: G_t PV (g1/g2) moved to MFMA with XOR-swizzled Pm + transposed hi/lo
//     Qv/Qo planes; QK^T+exp stays scalar fp32 (precision). g1/g2 output is
//     PLANAR per-(row,h) slice: g1 = ushorts [0,32), g2 = [32,64) of each
//     128B slice, in-place over the quR plane (same alias discipline as v7).
#define LOG2T_16 0.8304820237218406f  // log2(10000)/16

typedef __attribute__((ext_vector_type(8))) short short8;
typedef __attribute__((ext_vector_type(4))) float f32x4;

#define PERM_LO 0x05040100u  // [x.b0,x.b1,y.b0,y.b1] from perm(y,x,sel)
#define PERM_HI 0x07060302u  // [x.b2,x.b3,y.b2,y.b3]

__device__ __forceinline__ float bf2f(unsigned short u) {
    union { float f; unsigned int i; } x; x.i = ((unsigned int)u) << 16; return x.f;
}
__device__ __forceinline__ unsigned short f2b(float f) {
    __hip_bfloat16 h = __float2bfloat16(f);
    union { __hip_bfloat16 h; unsigned short u; } x; x.h = h; return x.u;
}

__device__ __forceinline__ float v5_dot32(const float* qurow, const float* row) {
    float dot = 0.f;
#pragma unroll
    for (int q = 0; q < 8; q++) {
        float4 x = *(const float4*)(row + q * 4);
        dot = fmaf(qurow[q * 4 + 0], x.x, dot);
        dot = fmaf(qurow[q * 4 + 1], x.y, dot);
        dot = fmaf(qurow[q * 4 + 2], x.z, dot);
        dot = fmaf(qurow[q * 4 + 3], x.w, dot);
    }
    return dot;
}

__device__ __forceinline__ void v5_fma32(float p_, const float* row, float* acc) {
#pragma unroll
    for (int q = 0; q < 8; q++) {
        float4 x = *(const float4*)(row + q * 4);
        float xs[4] = {x.x, x.y, x.z, x.w};
#pragma unroll
        for (int i = 0; i < 4; i++)
            acc[q * 4 + i] = fmaf(p_, xs[i], acc[q * 4 + i]);
    }
}

// ---------- K0: prep B planes for MFMA outgemm: transpose u,v and split into
// packed bf16 hi|lo uints:  Bp[mtx][c][k] = bf16hi(u[k][c]) | bf16lo<<16 ----------
__global__ __launch_bounds__(256) void v7_prepB(
    const float* __restrict__ u_t, const float* __restrict__ v_t,
    const float* __restrict__ u_c, const float* __restrict__ v_c,
    unsigned int* __restrict__ Bp)
{
    __shared__ float Ts[64][65];
    const int mtx = blockIdx.y;
    const float* src = (mtx == 0) ? u_t : (mtx == 1) ? v_t : (mtx == 2) ? u_c : v_c;
    unsigned int* dst = Bp + (size_t)mtx * 65536;
    const int k0 = (blockIdx.x >> 2) * 64;
    const int c0 = (blockIdx.x & 3) * 64;
    const int tid = threadIdx.x;
    const int lr = tid >> 2;              // 0..63
    const int lc0 = (tid & 3) * 16;
#pragma unroll
    for (int q = 0; q < 4; q++) {
        float4 x = *(const float4*)(src + (size_t)(k0 + lr) * 256 + c0 + lc0 + q * 4);
        *(float4*)&Ts[lr][lc0 + q * 4] = x;     // Ts[k_local][c_local]
    }
    __syncthreads();
#pragma unroll
    for (int q = 0; q < 4; q++) {
        unsigned int w[4];
#pragma unroll
        for (int e = 0; e < 4; e++) {
            float x = Ts[lc0 + q * 4 + e][lr];
            unsigned short hi = f2b(x);
            unsigned short lo = f2b(x - bf2f(hi));
            w[e] = (unsigned int)hi | ((unsigned int)lo << 16);
        }
        *(uint4*)(dst + (size_t)(c0 + lr) * 256 + k0 + lc0 + q * 4) =
            make_uint4(w[0], w[1], w[2], w[3]);
    }
}

// ---------- K1: [qu_rot | qv_rot] = RoPE(qz @ [u;v]^T), 64x64 tiles ----------
__global__ __launch_bounds__(256) void v5_proj(
    const float* __restrict__ qz, const float* __restrict__ u, const float* __restrict__ v,
    float* __restrict__ qu_rot, float* __restrict__ qv_rot, int chan, int posmask)
{
    __shared__ float As[16][68];
    __shared__ float Bs[16][68];
    __shared__ float Ct[64][68];
    const int row0 = blockIdx.x * 64;
    const int col0 = blockIdx.y * 64;               // 0..511
    const float* Bsrc = (col0 < 256) ? (u + col0 * 256) : (v + (col0 - 256) * 256);
    float* Cout = (col0 < 256) ? qu_rot : qv_rot;
    const int ccol0 = col0 & 255;
    const int tid = threadIdx.x;

    const int am = tid >> 2;
    const int ak = (tid & 3) * 4;
    int arow = row0 + am;
    if (chan) {
        int b = arow >> 12, p = (arow >> 5) & 127, c = arow & 31;
        arow = (b * 32 + c) * 128 + p;
    }
    const float* aptr = qz + (size_t)arow * 256 + ak;
    const float* bptr = Bsrc + (size_t)am * 256 + ak;

    const int tm = tid >> 4, tn = tid & 15;
    float acc[4][4] = {};
    for (int k0 = 0; k0 < 256; k0 += 16) {
        float4 a4 = *(const float4*)(aptr + k0);
        float4 b4 = *(const float4*)(bptr + k0);
        As[ak + 0][am] = a4.x; As[ak + 1][am] = a4.y; As[ak + 2][am] = a4.z; As[ak + 3][am] = a4.w;
        Bs[ak + 0][am] = b4.x; Bs[ak + 1][am] = b4.y; Bs[ak + 2][am] = b4.z; Bs[ak + 3][am] = b4.w;
        __syncthreads();
#pragma unroll
        for (int kk = 0; kk < 16; kk++) {
            float4 av = *(const float4*)&As[kk][tm * 4];
            float4 bv = *(const float4*)&Bs[kk][tn * 4];
            float ar[4] = {av.x, av.y, av.z, av.w};
            float br[4] = {bv.x, bv.y, bv.z, bv.w};
#pragma unroll
            for (int i = 0; i < 4; i++)
#pragma unroll
                for (int j = 0; j < 4; j++)
                    acc[i][j] = fmaf(ar[i], br[j], acc[i][j]);
        }
        __syncthreads();
    }
#pragma unroll
    for (int i = 0; i < 4; i++)
        *(float4*)&Ct[tm * 4 + i][tn * 4] = make_float4(acc[i][0], acc[i][1], acc[i][2], acc[i][3]);
    __syncthreads();
    const int r_local = tid >> 2;
    const int fj = (tid & 3) * 8;
    const int m = row0 + r_local;
    const float pos = (float)(m & posmask);
#pragma unroll
    for (int qq = 0; qq < 2; qq++) {
        int fhp = fj + qq * 4;                      // 0..28 step 4
        int hl = fhp >> 4, j0 = fhp & 15;
        int cl = hl * 32 + j0;
        float4 a4 = *(const float4*)&Ct[r_local][cl];
        float4 b4 = *(const float4*)&Ct[r_local][cl + 16];
        float aa[4] = {a4.x, a4.y, a4.z, a4.w};
        float bb[4] = {b4.x, b4.y, b4.z, b4.w};
        float o1[4], o2[4];
#pragma unroll
        for (int i = 0; i < 4; i++) {
            float ang = pos * exp2f(-(float)(j0 + i) * LOG2T_16);
            float sn, cs;
            sincosf(ang, &sn, &cs);                 // precise: pre-softmax path
            o1[i] = aa[i] * cs - bb[i] * sn;        // apply
            o2[i] = bb[i] * cs + aa[i] * sn;
        }
        *(float4*)(Cout + (size_t)m * 256 + ccol0 + cl)      = make_float4(o1[0], o1[1], o1[2], o1[3]);
        *(float4*)(Cout + (size_t)m * 256 + ccol0 + cl + 16) = make_float4(o2[0], o2[1], o2[2], o2[3]);
    }
}

// ---------- K2: time-path partial softmax stats ----------
__global__ __launch_bounds__(256) void v5_stats_t(
    const float* __restrict__ quR, const float* __restrict__ qvR,
    const float* __restrict__ mask, float* __restrict__ omax, float* __restrict__ osum)
{
    __shared__ float Qv[128][36];
    const int bid = blockIdx.x;                 // n*8 + h
    const int n = bid >> 3, h = bid & 7;
    const int b = n >> 5, c = n & 31;
    const int tid = threadIdx.x;
    for (int idx = tid * 4; idx < 4096; idx += 1024) {
        int s = idx >> 5, r = idx & 31;
        *(float4*)&Qv[s][r] = *(const float4*)(qvR + ((size_t)(n * 128 + s)) * 256 + h * 32 + r);
    }
    const int s = tid >> 1, toff = (tid & 1) * 64;
    float qurow[32];
    const float* qptr = quR + ((size_t)(n * 128 + s)) * 256 + h * 32;
#pragma unroll
    for (int q = 0; q < 8; q++) {
        float4 x = *(const float4*)(qptr + q * 4);
        qurow[q * 4 + 0] = x.x; qurow[q * 4 + 1] = x.y; qurow[q * 4 + 2] = x.z; qurow[q * 4 + 3] = x.w;
    }
    __syncthreads();
    const float* mrow = mask + (size_t)n * 16384 + s * 128 + toff;
    float mx = -1e30f, sm = 0.f;
#pragma unroll 4
    for (int t = 0; t < 64; t++) {
        float dot = v5_dot32(qurow, &Qv[toff + t][0]);
        float vv = 256.f * (dot + mrow[t]);
        float nm = fmaxf(mx, vv);
        sm = sm * __expf(mx - nm) + __expf(vv - nm);
        mx = nm;
    }
    float omx = __shfl_xor(mx, 1);
    float osm = __shfl_xor(sm, 1);
    float fm = fmaxf(mx, omx);
    float fs = sm * __expf(mx - fm) + osm * __expf(omx - fm);
    if ((tid & 1) == 0) {
        int idx = ((b * 8 + h) * 32 + c) * 128 + s;
        omax[idx] = fm; osum[idx] = fs;
    }
}

// ---------- K3: chan-path partial softmax stats ----------
__global__ __launch_bounds__(256) void v5_stats_c(
    const float* __restrict__ quR, const float* __restrict__ qvR,
    const float* __restrict__ mask, float* __restrict__ omax, float* __restrict__ osum)
{
    __shared__ float Qv[32][260];
    const int m = blockIdx.x;                   // b*128 + p
    const int b = m >> 7, p = m & 127;
    const int tid = threadIdx.x;
    for (int idx = tid * 4; idx < 8192; idx += 1024) {
        int sc = idx >> 8, dd = idx & 255;
        *(float4*)&Qv[sc][dd] = *(const float4*)(qvR + ((size_t)m * 32 + sc) * 256 + dd);
    }
    const int h = tid >> 5, sc = tid & 31;
    float qurow[32];
    const float* qptr = quR + ((size_t)m * 32 + sc) * 256 + h * 32;
#pragma unroll
    for (int q = 0; q < 8; q++) {
        float4 x = *(const float4*)(qptr + q * 4);
        qurow[q * 4 + 0] = x.x; qurow[q * 4 + 1] = x.y; qurow[q * 4 + 2] = x.z; qurow[q * 4 + 3] = x.w;
    }
    __syncthreads();
    const float* mrow = mask + (size_t)m * 1024 + sc * 32;
    float mx = -1e30f, sm = 0.f;
#pragma unroll 4
    for (int t = 0; t < 32; t++) {
        float dot = v5_dot32(qurow, &Qv[t][h * 32]);
        float vv = 256.f * (dot + mrow[t]);
        float nm = fmaxf(mx, vv);
        sm = sm * __expf(mx - nm) + __expf(vv - nm);
        mx = nm;
    }
    int idx = ((b * 8 + h) * 32 + sc) * 128 + p;
    omax[idx] = mx; osum[idx] = sm;
}

// ---------- K4: merge joint-softmax stats ----------
__global__ __launch_bounds__(256) void v5_merge(
    const float* __restrict__ mt, const float* __restrict__ st,
    const float* __restrict__ mc, const float* __restrict__ sc,
    float* __restrict__ Mo, float* __restrict__ So)
{
    int i = blockIdx.x * 256 + threadIdx.x;
    float a = mt[i], b = mc[i];
    float mx = fmaxf(a, b);
    float s = st[i] * __expf(a - mx) + sc[i] * __expf(b - mx);
    Mo[i] = mx;
    So[i] = 1.f / s;
}

// ---------- K5 v8: time-path G with MFMA PV. Scalar fp32 QK^T+exp -> swizzled
// Pm; g1 = P@Qv, g2T = QoT@P via mfma_16x16x32_bf16 (Qv/Qo hi+lo split).
// Planar output slices; rotated g1/g2 held in regs past the last quR read. ----------
__global__ __launch_bounds__(256) void v8_G_t(
    const float* quR, const float* qvR,
    const float* __restrict__ mask, const float* __restrict__ Mr, const float* __restrict__ Sv,
    unsigned short* gpl)
{
    __shared__ __align__(16) unsigned short Pm[16384];  // [128][128] XOR-swizzled
    __shared__ __align__(16) float Qv[128][36];         // fp32 (P phase); then QT u16 planes
    unsigned short* QT = (unsigned short*)&Qv[0][0];    // hi[32][128] @0, lo @4096
    const int bid = blockIdx.x;
    const int n = bid >> 3, h = bid & 7;
    const int b = n >> 5, c = n & 31;
    const int tid = threadIdx.x;
    const int lane = tid & 63, wv = tid >> 6;
    const int fr = lane & 15, kgl = lane >> 4;

    // phase 0: stage Qv fp32
    for (int idx = tid * 4; idx < 4096; idx += 1024) {
        int s = idx >> 5, r = idx & 31;
        *(float4*)&Qv[s][r] = *(const float4*)(qvR + ((size_t)(n * 128 + s)) * 256 + h * 32 + r);
    }
    // phase 1: P (scalar fp32 QK^T + exp) -> Pm swizzled
    {
        const int s = tid >> 1, toff = (tid & 1) * 64;
        float qurow[32];
        const float* qptr = quR + ((size_t)(n * 128 + s)) * 256 + h * 32;
#pragma unroll
        for (int q = 0; q < 8; q++) {
            float4 x = *(const float4*)(qptr + q * 4);
            qurow[q * 4 + 0] = x.x; qurow[q * 4 + 1] = x.y; qurow[q * 4 + 2] = x.z; qurow[q * 4 + 3] = x.w;
        }
        __syncthreads();
        const int rowidx = ((b * 8 + h) * 32 + c) * 128 + s;
        const float Mx = Mr[rowidx];
        const float Si = Sv[rowidx];
        const float* mrow = mask + (size_t)n * 16384 + s * 128 + toff;
#pragma unroll 4
        for (int t = 0; t < 64; t++) {
            float dot = v5_dot32(qurow, &Qv[toff + t][0]);
            float pv = __expf(256.f * (dot + mrow[t]) - Mx) * Si;
            int tg = toff + t;
            int ct = (((tg >> 3) ^ (s & 15)) << 3) | (tg & 7);
            Pm[s * 128 + ct] = f2b(pv);
        }
    }
    __syncthreads();
    // phase 2: build QvT hi/lo (transposed, swizzled) from GLOBAL qvR; overwrites Qv
    {
        const int t = tid >> 1, rh = (tid & 1) * 16;
        const float* src = qvR + ((size_t)(n * 128 + t)) * 256 + h * 32 + rh;
        float v[16];
#pragma unroll
        for (int q = 0; q < 4; q++)
            *(float4*)&v[q * 4] = *(const float4*)(src + q * 4);
#pragma unroll
        for (int i = 0; i < 16; i++) {
            int r = rh + i;
            unsigned short hi = f2b(v[i]);
            unsigned short lo = f2b(v[i] - bf2f(hi));
            int ct = (((t >> 3) ^ (r & 15)) << 3) | (t & 7);
            QT[r * 128 + ct] = hi;
            QT[4096 + r * 128 + ct] = lo;
        }
    }
    __syncthreads();
    // phase 3: g1 = P @ Qv (MFMA), rotate (apply_o, pos=s) -> regs
    unsigned int g1h[8];
    {
        f32x4 acc[2][2] = {};
#pragma unroll
        for (int kw = 0; kw < 4; kw++) {
            short8 a[2];
#pragma unroll
            for (int i = 0; i < 2; i++) {
                int row = wv * 32 + i * 16 + fr;
                a[i] = *(const short8*)&Pm[row * 128 + (((kw * 4 + kgl) ^ (row & 15)) << 3)];
            }
            short8 bh[2], bl[2];
#pragma unroll
            for (int j = 0; j < 2; j++) {
                int r = j * 16 + fr;
                int off = r * 128 + (((kw * 4 + kgl) ^ (r & 15)) << 3);
                bh[j] = *(const short8*)&QT[off];
                bl[j] = *(const short8*)&QT[4096 + off];
            }
#pragma unroll
            for (int i = 0; i < 2; i++)
#pragma unroll
                for (int j = 0; j < 2; j++) {
                    acc[i][j] = __builtin_amdgcn_mfma_f32_16x16x32_bf16(a[i], bh[j], acc[i][j], 0, 0, 0);
                    acc[i][j] = __builtin_amdgcn_mfma_f32_16x16x32_bf16(a[i], bl[j], acc[i][j], 0, 0, 0);
                }
        }
#pragma unroll
        for (int i = 0; i < 2; i++)
#pragma unroll
            for (int reg = 0; reg < 4; reg++) {
                int s = wv * 32 + i * 16 + kgl * 4 + reg;
                float ang = (float)s * exp2f(-(float)fr * LOG2T_16);
                float sn, cs;
                __sincosf(ang, &sn, &cs);
                float x = acc[i][0][reg], y = acc[i][1][reg];
                g1h[i * 4 + reg] = (unsigned int)f2b(x * cs + y * sn)
                                 | ((unsigned int)f2b(y * cs - x * sn) << 16);
            }
    }
    __syncthreads();
    // phase 4: build QoT hi/lo = R(-2theta)*quR transposed (LAST quR reads)
    {
        const int t = tid >> 1, jh = (tid & 1) * 8;
        const float* base = quR + ((size_t)(n * 128 + t)) * 256 + h * 32;
        float aa[8], bb[8];
        *(float4*)&aa[0] = *(const float4*)(base + jh);
        *(float4*)&aa[4] = *(const float4*)(base + jh + 4);
        *(float4*)&bb[0] = *(const float4*)(base + jh + 16);
        *(float4*)&bb[4] = *(const float4*)(base + jh + 20);
#pragma unroll
        for (int i = 0; i < 8; i++) {
            int j = jh + i;
            float ang = 2.f * (float)t * exp2f(-(float)j * LOG2T_16);
            float s2, c2;
            __sincosf(ang, &s2, &c2);
            float o1 = aa[i] * c2 + bb[i] * s2;   // col j
            float o2 = bb[i] * c2 - aa[i] * s2;   // col j+16
            int ct1 = (((t >> 3) ^ (j & 15)) << 3) | (t & 7);
            unsigned short h1 = f2b(o1);
            QT[j * 128 + ct1] = h1;
            QT[4096 + j * 128 + ct1] = f2b(o1 - bf2f(h1));
            int r2 = j + 16;
            int ct2 = (((t >> 3) ^ (r2 & 15)) << 3) | (t & 7);
            unsigned short h2 = f2b(o2);
            QT[r2 * 128 + ct2] = h2;
            QT[4096 + r2 * 128 + ct2] = f2b(o2 - bf2f(h2));
        }
    }
    __syncthreads();
    // phase 5: g2T = QoT @ P (B = Pm columns via swizzle), rotate (apply) -> regs
    unsigned int g2h[8];
    {
        f32x4 acc[2][2] = {};   // [r-tile][s-tile-local]
#pragma unroll
        for (int kw = 0; kw < 4; kw++) {
            short8 ah[2], al[2];
#pragma unroll
            for (int i = 0; i < 2; i++) {
                int r = i * 16 + fr;
                int off = r * 128 + (((kw * 4 + kgl) ^ (r & 15)) << 3);
                ah[i] = *(const short8*)&QT[off];
                al[i] = *(const short8*)&QT[4096 + off];
            }
            short8 bfr[2];
#pragma unroll
            for (int jj = 0; jj < 2; jj++) {
                int scol = (2 * wv + jj) * 16 + fr;
#pragma unroll
                for (int j = 0; j < 8; j++) {
                    int t = kw * 32 + kgl * 8 + j;
                    int ct = (((scol >> 3) ^ (t & 15)) << 3) | (scol & 7);
                    bfr[jj][j] = (short)Pm[t * 128 + ct];
                }
            }
#pragma unroll
            for (int i = 0; i < 2; i++)
#pragma unroll
                for (int jj = 0; jj < 2; jj++) {
                    acc[i][jj] = __builtin_amdgcn_mfma_f32_16x16x32_bf16(ah[i], bfr[jj], acc[i][jj], 0, 0, 0);
                    acc[i][jj] = __builtin_amdgcn_mfma_f32_16x16x32_bf16(al[i], bfr[jj], acc[i][jj], 0, 0, 0);
                }
        }
#pragma unroll
        for (int jj = 0; jj < 2; jj++)
#pragma unroll
            for (int reg = 0; reg < 4; reg++) {
                int sv = (2 * wv + jj) * 16 + fr;
                int r = kgl * 4 + reg;
                float ang = (float)sv * exp2f(-(float)r * LOG2T_16);
                float sn, cs;
                __sincosf(ang, &sn, &cs);
                float x = acc[0][jj][reg], y = acc[1][jj][reg];
                g2h[jj * 4 + reg] = (unsigned int)f2b(x * cs - y * sn)
                                  | ((unsigned int)f2b(y * cs + x * sn) << 16);
            }
    }
    __syncthreads();
    // phase 6: bounce rotated g1/g2 into Pm region ([s][32] u16 each)
    {
#pragma unroll
        for (int i = 0; i < 2; i++)
#pragma unroll
            for (int reg = 0; reg < 4; reg++) {
                int s = wv * 32 + i * 16 + kgl * 4 + reg;
                unsigned int w = g1h[i * 4 + reg];
                Pm[s * 32 + fr] = (unsigned short)w;
                Pm[s * 32 + fr + 16] = (unsigned short)(w >> 16);
            }
#pragma unroll
        for (int jj = 0; jj < 2; jj++)
#pragma unroll
            for (int reg = 0; reg < 4; reg++) {
                int s = (2 * wv + jj) * 16 + fr;
                int r = kgl * 4 + reg;
                unsigned int w = g2h[jj * 4 + reg];
                Pm[4096 + s * 32 + r] = (unsigned short)w;
                Pm[4096 + s * 32 + r + 16] = (unsigned short)(w >> 16);
            }
    }
    __syncthreads();
    // phase 7: coalesced planar stores (g1 at slice+0, g2 at slice+32 ushorts)
    {
        const int s = tid >> 1, rh = (tid & 1) * 16;
        size_t baseu = ((size_t)(n * 128 + s)) * 512 + h * 64 + rh;
        *(uint4*)(gpl + baseu)      = *(const uint4*)&Pm[s * 32 + rh];
        *(uint4*)(gpl + baseu + 8)  = *(const uint4*)&Pm[s * 32 + rh + 8];
        *(uint4*)(gpl + baseu + 32) = *(const uint4*)&Pm[4096 + s * 32 + rh];
        *(uint4*)(gpl + baseu + 40) = *(const uint4*)&Pm[4096 + s * 32 + rh + 8];
    }
}

// ---------- K6 v8: chan-path G, scalar (unchanged math), planar stores ----------
__global__ __launch_bounds__(256) void v8_G_c(
    const float* quR, const float* qvR,
    const float* __restrict__ mask, const float* __restrict__ Mr, const float* __restrict__ Sv,
    unsigned short* gpl)
{
    __shared__ float Qv[32][260];
    __shared__ unsigned short Pm[8][32][34];
    const int m = blockIdx.x;
    const int b = m >> 7, p = m & 127;
    const int tid = threadIdx.x;
    for (int idx = tid * 4; idx < 8192; idx += 1024) {
        int sc = idx >> 8, dd = idx & 255;
        *(float4*)&Qv[sc][dd] = *(const float4*)(qvR + ((size_t)m * 32 + sc) * 256 + dd);
    }
    const int h = tid >> 5, sc = tid & 31;
    {
        float qurow[32];
        const float* qptr = quR + ((size_t)m * 32 + sc) * 256 + h * 32;
#pragma unroll
        for (int q = 0; q < 8; q++) {
            float4 x = *(const float4*)(qptr + q * 4);
            qurow[q * 4 + 0] = x.x; qurow[q * 4 + 1] = x.y; qurow[q * 4 + 2] = x.z; qurow[q * 4 + 3] = x.w;
        }
        __syncthreads();
        const int rowidx = ((b * 8 + h) * 32 + sc) * 128 + p;
        const float Mx = Mr[rowidx], Si = Sv[rowidx];
        const float* mrow = mask + (size_t)m * 1024 + sc * 32;
#pragma unroll 4
        for (int t = 0; t < 32; t++) {
            float dot = v5_dot32(qurow, &Qv[t][h * 32]);
            float pv = __expf(256.f * (dot + mrow[t]) - Mx) * Si;
            Pm[h][t][sc] = f2b(pv);
        }
    }
    __syncthreads();
    float a[32] = {};
#pragma unroll 4
    for (int t = 0; t < 32; t++) {
        float p_ = bf2f(Pm[h][t][sc]);
        v5_fma32(p_, &Qv[t][h * 32], a);
    }
    float cs[16], sn[16];
#pragma unroll
    for (int i = 0; i < 16; i++) {
        float ang = (float)sc * exp2f(-(float)i * LOG2T_16);
        __sincosf(ang, &sn[i], &cs[i]);
    }
    unsigned int g1p[8], g1q[8];
#pragma unroll
    for (int j = 0; j < 8; j++) {
        int i0 = 2 * j, i1 = 2 * j + 1;
        float x0 = a[i0], y0 = a[16 + i0], x1 = a[i1], y1 = a[16 + i1];
        g1p[j] = (unsigned int)f2b(x0 * cs[i0] + y0 * sn[i0])
               | ((unsigned int)f2b(x1 * cs[i1] + y1 * sn[i1]) << 16);
        g1q[j] = (unsigned int)f2b(y0 * cs[i0] - x0 * sn[i0])
               | ((unsigned int)f2b(y1 * cs[i1] - x1 * sn[i1]) << 16);
    }
    __syncthreads();
    // restage Qo (LAST quR reads, before any gpl write)
    for (int idx = tid * 4; idx < 4096; idx += 1024) {
        int row = idx >> 7, rem = idx & 127;
        int h2 = rem >> 4, j0 = rem & 15;
        const float* base = quR + ((size_t)m * 32 + row) * 256 + h2 * 32;
        float4 a4 = *(const float4*)(base + j0);
        float4 b4 = *(const float4*)(base + j0 + 16);
        float aa[4] = {a4.x, a4.y, a4.z, a4.w};
        float bb[4] = {b4.x, b4.y, b4.z, b4.w};
        float o1[4], o2[4];
#pragma unroll
        for (int i = 0; i < 4; i++) {
            float ang = 2.f * (float)row * exp2f(-(float)(j0 + i) * LOG2T_16);
            float s2, c2;
            __sincosf(ang, &s2, &c2);
            o1[i] = aa[i] * c2 + bb[i] * s2;
            o2[i] = bb[i] * c2 - aa[i] * s2;
        }
        *(float4*)&Qv[row][h2 * 32 + j0]      = make_float4(o1[0], o1[1], o1[2], o1[3]);
        *(float4*)&Qv[row][h2 * 32 + j0 + 16] = make_float4(o2[0], o2[1], o2[2], o2[3]);
    }
    __syncthreads();
#pragma unroll
    for (int i = 0; i < 32; i++) a[i] = 0.f;
#pragma unroll 4
    for (int t = 0; t < 32; t++) {
        float p_ = bf2f(Pm[h][sc][t]);
        v5_fma32(p_, &Qv[t][h * 32], a);
    }
    // planar stores: g1 uints [0,16), g2 uints [16,32) of the (row,h) slice
    unsigned int* gpu = (unsigned int*)gpl;
    size_t ub = ((size_t)m * 32 + sc) * 256 + h * 32;
    *(uint4*)(gpu + ub)      = make_uint4(g1p[0], g1p[1], g1p[2], g1p[3]);
    *(uint4*)(gpu + ub + 4)  = make_uint4(g1p[4], g1p[5], g1p[6], g1p[7]);
    *(uint4*)(gpu + ub + 8)  = make_uint4(g1q[0], g1q[1], g1q[2], g1q[3]);
    *(uint4*)(gpu + ub + 12) = make_uint4(g1q[4], g1q[5], g1q[6], g1q[7]);
    unsigned int p2[8], q2[8];
#pragma unroll
    for (int j = 0; j < 8; j++) {
        int i0 = 2 * j, i1 = 2 * j + 1;
        p2[j] = (unsigned int)f2b(a[i0] * cs[i0] - a[16 + i0] * sn[i0])
              | ((unsigned int)f2b(a[i1] * cs[i1] - a[16 + i1] * sn[i1]) << 16);
        q2[j] = (unsigned int)f2b(a[16 + i0] * cs[i0] + a[i0] * sn[i0])
              | ((unsigned int)f2b(a[16 + i1] * cs[i1] + a[i1] * sn[i1]) << 16);
    }
    *(uint4*)(gpu + ub + 16) = make_uint4(p2[0], p2[1], p2[2], p2[3]);
    *(uint4*)(gpu + ub + 20) = make_uint4(p2[4], p2[5], p2[6], p2[7]);
    *(uint4*)(gpu + ub + 24) = make_uint4(q2[0], q2[1], q2[2], q2[3]);
    *(uint4*)(gpu + ub + 28) = make_uint4(q2[4], q2[5], q2[6], q2[7]);
}

// ---------- K7 v8: outgemm, planar A (g1/g2 slices), split-B MFMA ----------
__global__ __launch_bounds__(256) void v8_outgemm(
    const unsigned short* __restrict__ gpl,  // planar slices: g1 [0,32), g2 [32,64) per (row,h)
    const unsigned int* __restrict__ Bu,
    const unsigned int* __restrict__ Bv,
    float* __restrict__ out, int remap)
{
    __shared__ __align__(16) unsigned short A1[128][40];
    __shared__ __align__(16) unsigned short A2[128][40];
    __shared__ __align__(16) unsigned short Bh[2][128][40];
    __shared__ __align__(16) unsigned short Bl[2][128][40];
    const int row0 = blockIdx.x * 128;
    const int col0 = blockIdx.y * 128;
    const int tid = threadIdx.x;
    const int sr = tid >> 1;
    const int sk = (tid & 1) * 16;
    const int wv = tid >> 6;
    const int lane = tid & 63;
    const int wr = (wv >> 1) * 64, wc = (wv & 1) * 64;
    const int fr = lane & 15;
    const int fk = (lane >> 4) * 8;

    const unsigned int* uptr = Bu + (size_t)(col0 + sr) * 256 + sk;
    const unsigned int* vptr = Bv + (size_t)(col0 + sr) * 256 + sk;

    f32x4 acc[4][4] = {};

    for (int k0 = 0; k0 < 256; k0 += 32) {
        int kb = k0 + sk;
        const unsigned short* ap = gpl + (size_t)(row0 + sr) * 512 + ((kb >> 5) << 6) + (kb & 31);
        *(uint4*)&A1[sr][sk]     = *(const uint4*)ap;
        *(uint4*)&A1[sr][sk + 8] = *(const uint4*)(ap + 8);
        *(uint4*)&A2[sr][sk]     = *(const uint4*)(ap + 32);
        *(uint4*)&A2[sr][sk + 8] = *(const uint4*)(ap + 40);
#pragma unroll
        for (int q = 0; q < 4; q++) {
            uint4 wU = *(const uint4*)(uptr + k0 + q * 4);
            *(uint2*)&Bh[0][sr][sk + q * 4] = make_uint2(
                __builtin_amdgcn_perm(wU.y, wU.x, PERM_LO),
                __builtin_amdgcn_perm(wU.w, wU.z, PERM_LO));
            *(uint2*)&Bl[0][sr][sk + q * 4] = make_uint2(
                __builtin_amdgcn_perm(wU.y, wU.x, PERM_HI),
                __builtin_amdgcn_perm(wU.w, wU.z, PERM_HI));
            uint4 wV = *(const uint4*)(vptr + k0 + q * 4);
            *(uint2*)&Bh[1][sr][sk + q * 4] = make_uint2(
                __builtin_amdgcn_perm(wV.y, wV.x, PERM_LO),
                __builtin_amdgcn_perm(wV.w, wV.z, PERM_LO));
            *(uint2*)&Bl[1][sr][sk + q * 4] = make_uint2(
                __builtin_amdgcn_perm(wV.y, wV.x, PERM_HI),
                __builtin_amdgcn_perm(wV.w, wV.z, PERM_HI));
        }
        __syncthreads();
        short8 a1[4], a2[4];
#pragma unroll
        for (int i = 0; i < 4; i++) {
            a1[i] = *(const short8*)&A1[wr + i * 16 + fr][fk];
            a2[i] = *(const short8*)&A2[wr + i * 16 + fr][fk];
        }
#pragma unroll
        for (int j = 0; j < 4; j++) {
            const int bc = wc + j * 16 + fr;
            short8 buh = *(const short8*)&Bh[0][bc][fk];
            short8 bul = *(const short8*)&Bl[0][bc][fk];
            short8 bvh = *(const short8*)&Bh[1][bc][fk];
            short8 bvl = *(const short8*)&Bl[1][bc][fk];
#pragma unroll
            for (int i = 0; i < 4; i++) {
                acc[i][j] = __builtin_amdgcn_mfma_f32_16x16x32_bf16(a1[i], buh, acc[i][j], 0, 0, 0);
                acc[i][j] = __builtin_amdgcn_mfma_f32_16x16x32_bf16(a1[i], bul, acc[i][j], 0, 0, 0);
                acc[i][j] = __builtin_amdgcn_mfma_f32_16x16x32_bf16(a2[i], bvh, acc[i][j], 0, 0, 0);
                acc[i][j] = __builtin_amdgcn_mfma_f32_16x16x32_bf16(a2[i], bvl, acc[i][j], 0, 0, 0);
            }
        }
        __syncthreads();
    }
#pragma unroll
    for (int i = 0; i < 4; i++) {
#pragma unroll
        for (int r = 0; r < 4; r++) {
            int mr = row0 + wr + i * 16 + (lane >> 4) * 4 + r;
            int orow = mr;
            if (remap) {
                int bb = mr >> 12, pp = (mr >> 5) & 127, cc = mr & 31;
                orow = (bb << 12) + (cc << 7) + pp;
            }
            float* op = out + (size_t)orow * 256 + col0 + wc + fr;
#pragma unroll
            for (int j = 0; j < 4; j++)
                op[j * 16] = acc[i][j][r];
        }
    }
}

extern "C" void kernel_launch(void* const* d_in, const int* in_sizes, int n_in,
                              void* d_out, int out_size, void* d_ws, size_t ws_size,
                              hipStream_t stream)
{
    (void)in_sizes; (void)n_in; (void)out_size; (void)ws_size;
    const float* qz     = (const float*)d_in[0];
    const float* mask_t = (const float*)d_in[1];
    const float* mask_c = (const float*)d_in[2];
    const float* u_time = (const float*)d_in[3];
    const float* v_time = (const float*)d_in[4];
    const float* u_chan = (const float*)d_in[5];
    const float* v_chan = (const float*)d_in[6];
    float* out = (float*)d_out;
    float* W = (float*)d_ws;

    float* quR_t = W;
    float* qvR_t = W + 8388608;
    float* quR_c = W + 16777216;
    float* qvR_c = W + 25165824;
    float* S     = W + 33554432;
    float* max_t = S;
    float* sum_t = S + 262144;
    float* max_c = S + 524288;
    float* sum_c = S + 786432;
    float* Mrow  = S + 1048576;
    float* Sinv  = S + 1310720;
    unsigned int* BP = (unsigned int*)(W + 35127296);
    unsigned short* GPt = (unsigned short*)quR_t;   // planar g1|g2 slices (alias)
    unsigned short* GPc = (unsigned short*)quR_c;

    dim3 blk(256);
    v7_prepB<<<dim3(16, 4), blk, 0, stream>>>(u_time, v_time, u_chan, v_chan, BP);
    v5_proj<<<dim3(512, 8), blk, 0, stream>>>(qz, u_time, v_time, quR_t, qvR_t, 0, 127);
    v5_proj<<<dim3(512, 8), blk, 0, stream>>>(qz, u_chan, v_chan, quR_c, qvR_c, 1, 31);
    v5_stats_t<<<2048, blk, 0, stream>>>(quR_t, qvR_t, mask_t, max_t, sum_t);
    v5_stats_c<<<1024, blk, 0, stream>>>(quR_c, qvR_c, mask_c, max_c, sum_c);
    v5_merge<<<1024, blk, 0, stream>>>(max_t, sum_t, max_c, sum_c, Mrow, Sinv);
    v8_G_t<<<2048, blk, 0, stream>>>(quR_t, qvR_t, mask_t, Mrow, Sinv, GPt);
    v8_outgemm<<<dim3(256, 2), blk, 0, stream>>>(GPt, BP, BP + 65536, out, 0);
    v8_G_c<<<1024, blk, 0, stream>>>(quR_c, qvR_c, mask_c, Mrow, Sinv, GPc);
    v8_outgemm<<<dim3(256, 2), blk, 0, stream>>>(GPc, BP + 131072, BP + 196608, out + 8388608, 1);
}

// Round 15
// 689.470 us; speedup vs baseline: 1.2129x; 1.0666x over previous
//
#include <hip/hip_runtime.h>
#include <hip/hip_bf16.h>
#include <math.h>

// B=8 C=32 P=128 D=256 H=8 R=32; time: 256 seqs x 128; chan: 1024 seqs x 32.
// v9: v8 + XCD co-location swizzle in stats_t/G_t (n = bid&255, h = bid>>8) so
//     the 8 h-blocks sharing one n's 64KB mask land on ONE XCD (bid%8 = n%8)
//     -> mask fetched once into that XCD's L2 instead of 8x from HBM.
#define LOG2T_16 0.8304820237218406f  // log2(10000)/16

typedef __attribute__((ext_vector_type(8))) short short8;
typedef __attribute__((ext_vector_type(4))) float f32x4;

#define PERM_LO 0x05040100u  // [x.b0,x.b1,y.b0,y.b1] from perm(y,x,sel)
#define PERM_HI 0x07060302u  // [x.b2,x.b3,y.b2,y.b3]

__device__ __forceinline__ float bf2f(unsigned short u) {
    union { float f; unsigned int i; } x; x.i = ((unsigned int)u) << 16; return x.f;
}
__device__ __forceinline__ unsigned short f2b(float f) {
    __hip_bfloat16 h = __float2bfloat16(f);
    union { __hip_bfloat16 h; unsigned short u; } x; x.h = h; return x.u;
}

__device__ __forceinline__ float v5_dot32(const float* qurow, const float* row) {
    float dot = 0.f;
#pragma unroll
    for (int q = 0; q < 8; q++) {
        float4 x = *(const float4*)(row + q * 4);
        dot = fmaf(qurow[q * 4 + 0], x.x, dot);
        dot = fmaf(qurow[q * 4 + 1], x.y, dot);
        dot = fmaf(qurow[q * 4 + 2], x.z, dot);
        dot = fmaf(qurow[q * 4 + 3], x.w, dot);
    }
    return dot;
}

__device__ __forceinline__ void v5_fma32(float p_, const float* row, float* acc) {
#pragma unroll
    for (int q = 0; q < 8; q++) {
        float4 x = *(const float4*)(row + q * 4);
        float xs[4] = {x.x, x.y, x.z, x.w};
#pragma unroll
        for (int i = 0; i < 4; i++)
            acc[q * 4 + i] = fmaf(p_, xs[i], acc[q * 4 + i]);
    }
}

// ---------- K0: prep B planes for MFMA outgemm (unchanged) ----------
__global__ __launch_bounds__(256) void v7_prepB(
    const float* __restrict__ u_t, const float* __restrict__ v_t,
    const float* __restrict__ u_c, const float* __restrict__ v_c,
    unsigned int* __restrict__ Bp)
{
    __shared__ float Ts[64][65];
    const int mtx = blockIdx.y;
    const float* src = (mtx == 0) ? u_t : (mtx == 1) ? v_t : (mtx == 2) ? u_c : v_c;
    unsigned int* dst = Bp + (size_t)mtx * 65536;
    const int k0 = (blockIdx.x >> 2) * 64;
    const int c0 = (blockIdx.x & 3) * 64;
    const int tid = threadIdx.x;
    const int lr = tid >> 2;              // 0..63
    const int lc0 = (tid & 3) * 16;
#pragma unroll
    for (int q = 0; q < 4; q++) {
        float4 x = *(const float4*)(src + (size_t)(k0 + lr) * 256 + c0 + lc0 + q * 4);
        *(float4*)&Ts[lr][lc0 + q * 4] = x;     // Ts[k_local][c_local]
    }
    __syncthreads();
#pragma unroll
    for (int q = 0; q < 4; q++) {
        unsigned int w[4];
#pragma unroll
        for (int e = 0; e < 4; e++) {
            float x = Ts[lc0 + q * 4 + e][lr];
            unsigned short hi = f2b(x);
            unsigned short lo = f2b(x - bf2f(hi));
            w[e] = (unsigned int)hi | ((unsigned int)lo << 16);
        }
        *(uint4*)(dst + (size_t)(c0 + lr) * 256 + k0 + lc0 + q * 4) =
            make_uint4(w[0], w[1], w[2], w[3]);
    }
}

// ---------- K1: [qu_rot | qv_rot] = RoPE(qz @ [u;v]^T), 64x64 tiles (unchanged) ----------
__global__ __launch_bounds__(256) void v5_proj(
    const float* __restrict__ qz, const float* __restrict__ u, const float* __restrict__ v,
    float* __restrict__ qu_rot, float* __restrict__ qv_rot, int chan, int posmask)
{
    __shared__ float As[16][68];
    __shared__ float Bs[16][68];
    __shared__ float Ct[64][68];
    const int row0 = blockIdx.x * 64;
    const int col0 = blockIdx.y * 64;               // 0..511
    const float* Bsrc = (col0 < 256) ? (u + col0 * 256) : (v + (col0 - 256) * 256);
    float* Cout = (col0 < 256) ? qu_rot : qv_rot;
    const int ccol0 = col0 & 255;
    const int tid = threadIdx.x;

    const int am = tid >> 2;
    const int ak = (tid & 3) * 4;
    int arow = row0 + am;
    if (chan) {
        int b = arow >> 12, p = (arow >> 5) & 127, c = arow & 31;
        arow = (b * 32 + c) * 128 + p;
    }
    const float* aptr = qz + (size_t)arow * 256 + ak;
    const float* bptr = Bsrc + (size_t)am * 256 + ak;

    const int tm = tid >> 4, tn = tid & 15;
    float acc[4][4] = {};
    for (int k0 = 0; k0 < 256; k0 += 16) {
        float4 a4 = *(const float4*)(aptr + k0);
        float4 b4 = *(const float4*)(bptr + k0);
        As[ak + 0][am] = a4.x; As[ak + 1][am] = a4.y; As[ak + 2][am] = a4.z; As[ak + 3][am] = a4.w;
        Bs[ak + 0][am] = b4.x; Bs[ak + 1][am] = b4.y; Bs[ak + 2][am] = b4.z; Bs[ak + 3][am] = b4.w;
        __syncthreads();
#pragma unroll
        for (int kk = 0; kk < 16; kk++) {
            float4 av = *(const float4*)&As[kk][tm * 4];
            float4 bv = *(const float4*)&Bs[kk][tn * 4];
            float ar[4] = {av.x, av.y, av.z, av.w};
            float br[4] = {bv.x, bv.y, bv.z, bv.w};
#pragma unroll
            for (int i = 0; i < 4; i++)
#pragma unroll
                for (int j = 0; j < 4; j++)
                    acc[i][j] = fmaf(ar[i], br[j], acc[i][j]);
        }
        __syncthreads();
    }
#pragma unroll
    for (int i = 0; i < 4; i++)
        *(float4*)&Ct[tm * 4 + i][tn * 4] = make_float4(acc[i][0], acc[i][1], acc[i][2], acc[i][3]);
    __syncthreads();
    const int r_local = tid >> 2;
    const int fj = (tid & 3) * 8;
    const int m = row0 + r_local;
    const float pos = (float)(m & posmask);
#pragma unroll
    for (int qq = 0; qq < 2; qq++) {
        int fhp = fj + qq * 4;                      // 0..28 step 4
        int hl = fhp >> 4, j0 = fhp & 15;
        int cl = hl * 32 + j0;
        float4 a4 = *(const float4*)&Ct[r_local][cl];
        float4 b4 = *(const float4*)&Ct[r_local][cl + 16];
        float aa[4] = {a4.x, a4.y, a4.z, a4.w};
        float bb[4] = {b4.x, b4.y, b4.z, b4.w};
        float o1[4], o2[4];
#pragma unroll
        for (int i = 0; i < 4; i++) {
            float ang = pos * exp2f(-(float)(j0 + i) * LOG2T_16);
            float sn, cs;
            sincosf(ang, &sn, &cs);                 // precise: pre-softmax path
            o1[i] = aa[i] * cs - bb[i] * sn;        // apply
            o2[i] = bb[i] * cs + aa[i] * sn;
        }
        *(float4*)(Cout + (size_t)m * 256 + ccol0 + cl)      = make_float4(o1[0], o1[1], o1[2], o1[3]);
        *(float4*)(Cout + (size_t)m * 256 + ccol0 + cl + 16) = make_float4(o2[0], o2[1], o2[2], o2[3]);
    }
}

// ---------- K2 v9: time-path stats; XCD co-location (n = bid&255) ----------
__global__ __launch_bounds__(256) void v5_stats_t(
    const float* __restrict__ quR, const float* __restrict__ qvR,
    const float* __restrict__ mask, float* __restrict__ omax, float* __restrict__ osum)
{
    __shared__ float Qv[128][36];
    const int bid = blockIdx.x;                 // v9: n = bid&255, h = bid>>8
    const int n = bid & 255, h = bid >> 8;      // same-n blocks -> same XCD (bid%8 = n%8)
    const int b = n >> 5, c = n & 31;
    const int tid = threadIdx.x;
    for (int idx = tid * 4; idx < 4096; idx += 1024) {
        int s = idx >> 5, r = idx & 31;
        *(float4*)&Qv[s][r] = *(const float4*)(qvR + ((size_t)(n * 128 + s)) * 256 + h * 32 + r);
    }
    const int s = tid >> 1, toff = (tid & 1) * 64;
    float qurow[32];
    const float* qptr = quR + ((size_t)(n * 128 + s)) * 256 + h * 32;
#pragma unroll
    for (int q = 0; q < 8; q++) {
        float4 x = *(const float4*)(qptr + q * 4);
        qurow[q * 4 + 0] = x.x; qurow[q * 4 + 1] = x.y; qurow[q * 4 + 2] = x.z; qurow[q * 4 + 3] = x.w;
    }
    __syncthreads();
    const float* mrow = mask + (size_t)n * 16384 + s * 128 + toff;
    float mx = -1e30f, sm = 0.f;
#pragma unroll 4
    for (int t = 0; t < 64; t++) {
        float dot = v5_dot32(qurow, &Qv[toff + t][0]);
        float vv = 256.f * (dot + mrow[t]);
        float nm = fmaxf(mx, vv);
        sm = sm * __expf(mx - nm) + __expf(vv - nm);
        mx = nm;
    }
    float omx = __shfl_xor(mx, 1);
    float osm = __shfl_xor(sm, 1);
    float fm = fmaxf(mx, omx);
    float fs = sm * __expf(mx - fm) + osm * __expf(omx - fm);
    if ((tid & 1) == 0) {
        int idx = ((b * 8 + h) * 32 + c) * 128 + s;
        omax[idx] = fm; osum[idx] = fs;
    }
}

// ---------- K3: chan-path partial softmax stats (unchanged; mask not shared) ----------
__global__ __launch_bounds__(256) void v5_stats_c(
    const float* __restrict__ quR, const float* __restrict__ qvR,
    const float* __restrict__ mask, float* __restrict__ omax, float* __restrict__ osum)
{
    __shared__ float Qv[32][260];
    const int m = blockIdx.x;                   // b*128 + p
    const int b = m >> 7, p = m & 127;
    const int tid = threadIdx.x;
    for (int idx = tid * 4; idx < 8192; idx += 1024) {
        int sc = idx >> 8, dd = idx & 255;
        *(float4*)&Qv[sc][dd] = *(const float4*)(qvR + ((size_t)m * 32 + sc) * 256 + dd);
    }
    const int h = tid >> 5, sc = tid & 31;
    float qurow[32];
    const float* qptr = quR + ((size_t)m * 32 + sc) * 256 + h * 32;
#pragma unroll
    for (int q = 0; q < 8; q++) {
        float4 x = *(const float4*)(qptr + q * 4);
        qurow[q * 4 + 0] = x.x; qurow[q * 4 + 1] = x.y; qurow[q * 4 + 2] = x.z; qurow[q * 4 + 3] = x.w;
    }
    __syncthreads();
    const float* mrow = mask + (size_t)m * 1024 + sc * 32;
    float mx = -1e30f, sm = 0.f;
#pragma unroll 4
    for (int t = 0; t < 32; t++) {
        float dot = v5_dot32(qurow, &Qv[t][h * 32]);
        float vv = 256.f * (dot + mrow[t]);
        float nm = fmaxf(mx, vv);
        sm = sm * __expf(mx - nm) + __expf(vv - nm);
        mx = nm;
    }
    int idx = ((b * 8 + h) * 32 + sc) * 128 + p;
    omax[idx] = mx; osum[idx] = sm;
}

// ---------- K4: merge joint-softmax stats (unchanged) ----------
__global__ __launch_bounds__(256) void v5_merge(
    const float* __restrict__ mt, const float* __restrict__ st,
    const float* __restrict__ mc, const float* __restrict__ sc,
    float* __restrict__ Mo, float* __restrict__ So)
{
    int i = blockIdx.x * 256 + threadIdx.x;
    float a = mt[i], b = mc[i];
    float mx = fmaxf(a, b);
    float s = st[i] * __expf(a - mx) + sc[i] * __expf(b - mx);
    Mo[i] = mx;
    So[i] = 1.f / s;
}

// ---------- K5 v9: time-path G with MFMA PV; XCD co-location (n = bid&255) ----------
__global__ __launch_bounds__(256) void v8_G_t(
    const float* quR, const float* qvR,
    const float* __restrict__ mask, const float* __restrict__ Mr, const float* __restrict__ Sv,
    unsigned short* gpl)
{
    __shared__ __align__(16) unsigned short Pm[16384];  // [128][128] XOR-swizzled
    __shared__ __align__(16) float Qv[128][36];         // fp32 (P phase); then QT u16 planes
    unsigned short* QT = (unsigned short*)&Qv[0][0];    // hi[32][128] @0, lo @4096
    const int bid = blockIdx.x;
    const int n = bid & 255, h = bid >> 8;      // v9: same-n blocks -> same XCD
    const int b = n >> 5, c = n & 31;
    const int tid = threadIdx.x;
    const int lane = tid & 63, wv = tid >> 6;
    const int fr = lane & 15, kgl = lane >> 4;

    // phase 0: stage Qv fp32
    for (int idx = tid * 4; idx < 4096; idx += 1024) {
        int s = idx >> 5, r = idx & 31;
        *(float4*)&Qv[s][r] = *(const float4*)(qvR + ((size_t)(n * 128 + s)) * 256 + h * 32 + r);
    }
    // phase 1: P (scalar fp32 QK^T + exp) -> Pm swizzled
    {
        const int s = tid >> 1, toff = (tid & 1) * 64;
        float qurow[32];
        const float* qptr = quR + ((size_t)(n * 128 + s)) * 256 + h * 32;
#pragma unroll
        for (int q = 0; q < 8; q++) {
            float4 x = *(const float4*)(qptr + q * 4);
            qurow[q * 4 + 0] = x.x; qurow[q * 4 + 1] = x.y; qurow[q * 4 + 2] = x.z; qurow[q * 4 + 3] = x.w;
        }
        __syncthreads();
        const int rowidx = ((b * 8 + h) * 32 + c) * 128 + s;
        const float Mx = Mr[rowidx];
        const float Si = Sv[rowidx];
        const float* mrow = mask + (size_t)n * 16384 + s * 128 + toff;
#pragma unroll 4
        for (int t = 0; t < 64; t++) {
            float dot = v5_dot32(qurow, &Qv[toff + t][0]);
            float pv = __expf(256.f * (dot + mrow[t]) - Mx) * Si;
            int tg = toff + t;
            int ct = (((tg >> 3) ^ (s & 15)) << 3) | (tg & 7);
            Pm[s * 128 + ct] = f2b(pv);
        }
    }
    __syncthreads();
    // phase 2: build QvT hi/lo (transposed, swizzled) from GLOBAL qvR; overwrites Qv
    {
        const int t = tid >> 1, rh = (tid & 1) * 16;
        const float* src = qvR + ((size_t)(n * 128 + t)) * 256 + h * 32 + rh;
        float v[16];
#pragma unroll
        for (int q = 0; q < 4; q++)
            *(float4*)&v[q * 4] = *(const float4*)(src + q * 4);
#pragma unroll
        for (int i = 0; i < 16; i++) {
            int r = rh + i;
            unsigned short hi = f2b(v[i]);
            unsigned short lo = f2b(v[i] - bf2f(hi));
            int ct = (((t >> 3) ^ (r & 15)) << 3) | (t & 7);
            QT[r * 128 + ct] = hi;
            QT[4096 + r * 128 + ct] = lo;
        }
    }
    __syncthreads();
    // phase 3: g1 = P @ Qv (MFMA), rotate (apply_o, pos=s) -> regs
    unsigned int g1h[8];
    {
        f32x4 acc[2][2] = {};
#pragma unroll
        for (int kw = 0; kw < 4; kw++) {
            short8 a[2];
#pragma unroll
            for (int i = 0; i < 2; i++) {
                int row = wv * 32 + i * 16 + fr;
                a[i] = *(const short8*)&Pm[row * 128 + (((kw * 4 + kgl) ^ (row & 15)) << 3)];
            }
            short8 bh[2], bl[2];
#pragma unroll
            for (int j = 0; j < 2; j++) {
                int r = j * 16 + fr;
                int off = r * 128 + (((kw * 4 + kgl) ^ (r & 15)) << 3);
                bh[j] = *(const short8*)&QT[off];
                bl[j] = *(const short8*)&QT[4096 + off];
            }
#pragma unroll
            for (int i = 0; i < 2; i++)
#pragma unroll
                for (int j = 0; j < 2; j++) {
                    acc[i][j] = __builtin_amdgcn_mfma_f32_16x16x32_bf16(a[i], bh[j], acc[i][j], 0, 0, 0);
                    acc[i][j] = __builtin_amdgcn_mfma_f32_16x16x32_bf16(a[i], bl[j], acc[i][j], 0, 0, 0);
                }
        }
#pragma unroll
        for (int i = 0; i < 2; i++)
#pragma unroll
            for (int reg = 0; reg < 4; reg++) {
                int s = wv * 32 + i * 16 + kgl * 4 + reg;
                float ang = (float)s * exp2f(-(float)fr * LOG2T_16);
                float sn, cs;
                __sincosf(ang, &sn, &cs);
                float x = acc[i][0][reg], y = acc[i][1][reg];
                g1h[i * 4 + reg] = (unsigned int)f2b(x * cs + y * sn)
                                 | ((unsigned int)f2b(y * cs - x * sn) << 16);
            }
    }
    __syncthreads();
    // phase 4: build QoT hi/lo = R(-2theta)*quR transposed (LAST quR reads)
    {
        const int t = tid >> 1, jh = (tid & 1) * 8;
        const float* base = quR + ((size_t)(n * 128 + t)) * 256 + h * 32;
        float aa[8], bb[8];
        *(float4*)&aa[0] = *(const float4*)(base + jh);
        *(float4*)&aa[4] = *(const float4*)(base + jh + 4);
        *(float4*)&bb[0] = *(const float4*)(base + jh + 16);
        *(float4*)&bb[4] = *(const float4*)(base + jh + 20);
#pragma unroll
        for (int i = 0; i < 8; i++) {
            int j = jh + i;
            float ang = 2.f * (float)t * exp2f(-(float)j * LOG2T_16);
            float s2, c2;
            __sincosf(ang, &s2, &c2);
            float o1 = aa[i] * c2 + bb[i] * s2;   // col j
            float o2 = bb[i] * c2 - aa[i] * s2;   // col j+16
            int ct1 = (((t >> 3) ^ (j & 15)) << 3) | (t & 7);
            unsigned short h1 = f2b(o1);
            QT[j * 128 + ct1] = h1;
            QT[4096 + j * 128 + ct1] = f2b(o1 - bf2f(h1));
            int r2 = j + 16;
            int ct2 = (((t >> 3) ^ (r2 & 15)) << 3) | (t & 7);
            unsigned short h2 = f2b(o2);
            QT[r2 * 128 + ct2] = h2;
            QT[4096 + r2 * 128 + ct2] = f2b(o2 - bf2f(h2));
        }
    }
    __syncthreads();
    // phase 5: g2T = QoT @ P (B = Pm columns via swizzle), rotate (apply) -> regs
    unsigned int g2h[8];
    {
        f32x4 acc[2][2] = {};   // [r-tile][s-tile-local]
#pragma unroll
        for (int kw = 0; kw < 4; kw++) {
            short8 ah[2], al[2];
#pragma unroll
            for (int i = 0; i < 2; i++) {
                int r = i * 16 + fr;
                int off = r * 128 + (((kw * 4 + kgl) ^ (r & 15)) << 3);
                ah[i] = *(const short8*)&QT[off];
                al[i] = *(const short8*)&QT[4096 + off];
            }
            short8 bfr[2];
#pragma unroll
            for (int jj = 0; jj < 2; jj++) {
                int scol = (2 * wv + jj) * 16 + fr;
#pragma unroll
                for (int j = 0; j < 8; j++) {
                    int t = kw * 32 + kgl * 8 + j;
                    int ct = (((scol >> 3) ^ (t & 15)) << 3) | (scol & 7);
                    bfr[jj][j] = (short)Pm[t * 128 + ct];
                }
            }
#pragma unroll
            for (int i = 0; i < 2; i++)
#pragma unroll
                for (int jj = 0; jj < 2; jj++) {
                    acc[i][jj] = __builtin_amdgcn_mfma_f32_16x16x32_bf16(ah[i], bfr[jj], acc[i][jj], 0, 0, 0);
                    acc[i][jj] = __builtin_amdgcn_mfma_f32_16x16x32_bf16(al[i], bfr[jj], acc[i][jj], 0, 0, 0);
                }
        }
#pragma unroll
        for (int jj = 0; jj < 2; jj++)
#pragma unroll
            for (int reg = 0; reg < 4; reg++) {
                int sv = (2 * wv + jj) * 16 + fr;
                int r = kgl * 4 + reg;
                float ang = (float)sv * exp2f(-(float)r * LOG2T_16);
                float sn, cs;
                __sincosf(ang, &sn, &cs);
                float x = acc[0][jj][reg], y = acc[1][jj][reg];
                g2h[jj * 4 + reg] = (unsigned int)f2b(x * cs - y * sn)
                                  | ((unsigned int)f2b(y * cs + x * sn) << 16);
            }
    }
    __syncthreads();
    // phase 6: bounce rotated g1/g2 into Pm region ([s][32] u16 each)
    {
#pragma unroll
        for (int i = 0; i < 2; i++)
#pragma unroll
            for (int reg = 0; reg < 4; reg++) {
                int s = wv * 32 + i * 16 + kgl * 4 + reg;
                unsigned int w = g1h[i * 4 + reg];
                Pm[s * 32 + fr] = (unsigned short)w;
                Pm[s * 32 + fr + 16] = (unsigned short)(w >> 16);
            }
#pragma unroll
        for (int jj = 0; jj < 2; jj++)
#pragma unroll
            for (int reg = 0; reg < 4; reg++) {
                int s = (2 * wv + jj) * 16 + fr;
                int r = kgl * 4 + reg;
                unsigned int w = g2h[jj * 4 + reg];
                Pm[4096 + s * 32 + r] = (unsigned short)w;
                Pm[4096 + s * 32 + r + 16] = (unsigned short)(w >> 16);
            }
    }
    __syncthreads();
    // phase 7: coalesced planar stores (g1 at slice+0, g2 at slice+32 ushorts)
    {
        const int s = tid >> 1, rh = (tid & 1) * 16;
        size_t baseu = ((size_t)(n * 128 + s)) * 512 + h * 64 + rh;
        *(uint4*)(gpl + baseu)      = *(const uint4*)&Pm[s * 32 + rh];
        *(uint4*)(gpl + baseu + 8)  = *(const uint4*)&Pm[s * 32 + rh + 8];
        *(uint4*)(gpl + baseu + 32) = *(const uint4*)&Pm[4096 + s * 32 + rh];
        *(uint4*)(gpl + baseu + 40) = *(const uint4*)&Pm[4096 + s * 32 + rh + 8];
    }
}

// ---------- K6 v8: chan-path G, scalar (unchanged), planar stores ----------
__global__ __launch_bounds__(256) void v8_G_c(
    const float* quR, const float* qvR,
    const float* __restrict__ mask, const float* __restrict__ Mr, const float* __restrict__ Sv,
    unsigned short* gpl)
{
    __shared__ float Qv[32][260];
    __shared__ unsigned short Pm[8][32][34];
    const int m = blockIdx.x;
    const int b = m >> 7, p = m & 127;
    const int tid = threadIdx.x;
    for (int idx = tid * 4; idx < 8192; idx += 1024) {
        int sc = idx >> 8, dd = idx & 255;
        *(float4*)&Qv[sc][dd] = *(const float4*)(qvR + ((size_t)m * 32 + sc) * 256 + dd);
    }
    const int h = tid >> 5, sc = tid & 31;
    {
        float qurow[32];
        const float* qptr = quR + ((size_t)m * 32 + sc) * 256 + h * 32;
#pragma unroll
        for (int q = 0; q < 8; q++) {
            float4 x = *(const float4*)(qptr + q * 4);
            qurow[q * 4 + 0] = x.x; qurow[q * 4 + 1] = x.y; qurow[q * 4 + 2] = x.z; qurow[q * 4 + 3] = x.w;
        }
        __syncthreads();
        const int rowidx = ((b * 8 + h) * 32 + sc) * 128 + p;
        const float Mx = Mr[rowidx], Si = Sv[rowidx];
        const float* mrow = mask + (size_t)m * 1024 + sc * 32;
#pragma unroll 4
        for (int t = 0; t < 32; t++) {
            float dot = v5_dot32(qurow, &Qv[t][h * 32]);
            float pv = __expf(256.f * (dot + mrow[t]) - Mx) * Si;
            Pm[h][t][sc] = f2b(pv);
        }
    }
    __syncthreads();
    float a[32] = {};
#pragma unroll 4
    for (int t = 0; t < 32; t++) {
        float p_ = bf2f(Pm[h][t][sc]);
        v5_fma32(p_, &Qv[t][h * 32], a);
    }
    float cs[16], sn[16];
#pragma unroll
    for (int i = 0; i < 16; i++) {
        float ang = (float)sc * exp2f(-(float)i * LOG2T_16);
        __sincosf(ang, &sn[i], &cs[i]);
    }
    unsigned int g1p[8], g1q[8];
#pragma unroll
    for (int j = 0; j < 8; j++) {
        int i0 = 2 * j, i1 = 2 * j + 1;
        float x0 = a[i0], y0 = a[16 + i0], x1 = a[i1], y1 = a[16 + i1];
        g1p[j] = (unsigned int)f2b(x0 * cs[i0] + y0 * sn[i0])
               | ((unsigned int)f2b(x1 * cs[i1] + y1 * sn[i1]) << 16);
        g1q[j] = (unsigned int)f2b(y0 * cs[i0] - x0 * sn[i0])
               | ((unsigned int)f2b(y1 * cs[i1] - x1 * sn[i1]) << 16);
    }
    __syncthreads();
    // restage Qo (LAST quR reads, before any gpl write)
    for (int idx = tid * 4; idx < 4096; idx += 1024) {
        int row = idx >> 7, rem = idx & 127;
        int h2 = rem >> 4, j0 = rem & 15;
        const float* base = quR + ((size_t)m * 32 + row) * 256 + h2 * 32;
        float4 a4 = *(const float4*)(base + j0);
        float4 b4 = *(const float4*)(base + j0 + 16);
        float aa[4] = {a4.x, a4.y, a4.z, a4.w};
        float bb[4] = {b4.x, b4.y, b4.z, b4.w};
        float o1[4], o2[4];
#pragma unroll
        for (int i = 0; i < 4; i++) {
            float ang = 2.f * (float)row * exp2f(-(float)(j0 + i) * LOG2T_16);
            float s2, c2;
            __sincosf(ang, &s2, &c2);
            o1[i] = aa[i] * c2 + bb[i] * s2;
            o2[i] = bb[i] * c2 - aa[i] * s2;
        }
        *(float4*)&Qv[row][h2 * 32 + j0]      = make_float4(o1[0], o1[1], o1[2], o1[3]);
        *(float4*)&Qv[row][h2 * 32 + j0 + 16] = make_float4(o2[0], o2[1], o2[2], o2[3]);
    }
    __syncthreads();
#pragma unroll
    for (int i = 0; i < 32; i++) a[i] = 0.f;
#pragma unroll 4
    for (int t = 0; t < 32; t++) {
        float p_ = bf2f(Pm[h][sc][t]);
        v5_fma32(p_, &Qv[t][h * 32], a);
    }
    // planar stores: g1 uints [0,16), g2 uints [16,32) of the (row,h) slice
    unsigned int* gpu = (unsigned int*)gpl;
    size_t ub = ((size_t)m * 32 + sc) * 256 + h * 32;
    *(uint4*)(gpu + ub)      = make_uint4(g1p[0], g1p[1], g1p[2], g1p[3]);
    *(uint4*)(gpu + ub + 4)  = make_uint4(g1p[4], g1p[5], g1p[6], g1p[7]);
    *(uint4*)(gpu + ub + 8)  = make_uint4(g1q[0], g1q[1], g1q[2], g1q[3]);
    *(uint4*)(gpu + ub + 12) = make_uint4(g1q[4], g1q[5], g1q[6], g1q[7]);
    unsigned int p2[8], q2[8];
#pragma unroll
    for (int j = 0; j < 8; j++) {
        int i0 = 2 * j, i1 = 2 * j + 1;
        p2[j] = (unsigned int)f2b(a[i0] * cs[i0] - a[16 + i0] * sn[i0])
              | ((unsigned int)f2b(a[i1] * cs[i1] - a[16 + i1] * sn[i1]) << 16);
        q2[j] = (unsigned int)f2b(a[16 + i0] * cs[i0] + a[i0] * sn[i0])
              | ((unsigned int)f2b(a[16 + i1] * cs[i1] + a[i1] * sn[i1]) << 16);
    }
    *(uint4*)(gpu + ub + 16) = make_uint4(p2[0], p2[1], p2[2], p2[3]);
    *(uint4*)(gpu + ub + 20) = make_uint4(p2[4], p2[5], p2[6], p2[7]);
    *(uint4*)(gpu + ub + 24) = make_uint4(q2[0], q2[1], q2[2], q2[3]);
    *(uint4*)(gpu + ub + 28) = make_uint4(q2[4], q2[5], q2[6], q2[7]);
}

// ---------- K7 v8: outgemm, planar A (g1/g2 slices), split-B MFMA (unchanged) ----------
__global__ __launch_bounds__(256) void v8_outgemm(
    const unsigned short* __restrict__ gpl,  // planar slices: g1 [0,32), g2 [32,64) per (row,h)
    const unsigned int* __restrict__ Bu,
    const unsigned int* __restrict__ Bv,
    float* __restrict__ out, int remap)
{
    __shared__ __align__(16) unsigned short A1[128][40];
    __shared__ __align__(16) unsigned short A2[128][40];
    __shared__ __align__(16) unsigned short Bh[2][128][40];
    __shared__ __align__(16) unsigned short Bl[2][128][40];
    const int row0 = blockIdx.x * 128;
    const int col0 = blockIdx.y * 128;
    const int tid = threadIdx.x;
    const int sr = tid >> 1;
    const int sk = (tid & 1) * 16;
    const int wv = tid >> 6;
    const int lane = tid & 63;
    const int wr = (wv >> 1) * 64, wc = (wv & 1) * 64;
    const int fr = lane & 15;
    const int fk = (lane >> 4) * 8;

    const unsigned int* uptr = Bu + (size_t)(col0 + sr) * 256 + sk;
    const unsigned int* vptr = Bv + (size_t)(col0 + sr) * 256 + sk;

    f32x4 acc[4][4] = {};

    for (int k0 = 0; k0 < 256; k0 += 32) {
        int kb = k0 + sk;
        const unsigned short* ap = gpl + (size_t)(row0 + sr) * 512 + ((kb >> 5) << 6) + (kb & 31);
        *(uint4*)&A1[sr][sk]     = *(const uint4*)ap;
        *(uint4*)&A1[sr][sk + 8] = *(const uint4*)(ap + 8);
        *(uint4*)&A2[sr][sk]     = *(const uint4*)(ap + 32);
        *(uint4*)&A2[sr][sk + 8] = *(const uint4*)(ap + 40);
#pragma unroll
        for (int q = 0; q < 4; q++) {
            uint4 wU = *(const uint4*)(uptr + k0 + q * 4);
            *(uint2*)&Bh[0][sr][sk + q * 4] = make_uint2(
                __builtin_amdgcn_perm(wU.y, wU.x, PERM_LO),
                __builtin_amdgcn_perm(wU.w, wU.z, PERM_LO));
            *(uint2*)&Bl[0][sr][sk + q * 4] = make_uint2(
                __builtin_amdgcn_perm(wU.y, wU.x, PERM_HI),
                __builtin_amdgcn_perm(wU.w, wU.z, PERM_HI));
            uint4 wV = *(const uint4*)(vptr + k0 + q * 4);
            *(uint2*)&Bh[1][sr][sk + q * 4] = make_uint2(
                __builtin_amdgcn_perm(wV.y, wV.x, PERM_LO),
                __builtin_amdgcn_perm(wV.w, wV.z, PERM_LO));
            *(uint2*)&Bl[1][sr][sk + q * 4] = make_uint2(
                __builtin_amdgcn_perm(wV.y, wV.x, PERM_HI),
                __builtin_amdgcn_perm(wV.w, wV.z, PERM_HI));
        }
        __syncthreads();
        short8 a1[4], a2[4];
#pragma unroll
        for (int i = 0; i < 4; i++) {
            a1[i] = *(const short8*)&A1[wr + i * 16 + fr][fk];
            a2[i] = *(const short8*)&A2[wr + i * 16 + fr][fk];
        }
#pragma unroll
        for (int j = 0; j < 4; j++) {
            const int bc = wc + j * 16 + fr;
            short8 buh = *(const short8*)&Bh[0][bc][fk];
            short8 bul = *(const short8*)&Bl[0][bc][fk];
            short8 bvh = *(const short8*)&Bh[1][bc][fk];
            short8 bvl = *(const short8*)&Bl[1][bc][fk];
#pragma unroll
            for (int i = 0; i < 4; i++) {
                acc[i][j] = __builtin_amdgcn_mfma_f32_16x16x32_bf16(a1[i], buh, acc[i][j], 0, 0, 0);
                acc[i][j] = __builtin_amdgcn_mfma_f32_16x16x32_bf16(a1[i], bul, acc[i][j], 0, 0, 0);
                acc[i][j] = __builtin_amdgcn_mfma_f32_16x16x32_bf16(a2[i], bvh, acc[i][j], 0, 0, 0);
                acc[i][j] = __builtin_amdgcn_mfma_f32_16x16x32_bf16(a2[i], bvl, acc[i][j], 0, 0, 0);
            }
        }
        __syncthreads();
    }
#pragma unroll
    for (int i = 0; i < 4; i++) {
#pragma unroll
        for (int r = 0; r < 4; r++) {
            int mr = row0 + wr + i * 16 + (lane >> 4) * 4 + r;
            int orow = mr;
            if (remap) {
                int bb = mr >> 12, pp = (mr >> 5) & 127, cc = mr & 31;
                orow = (bb << 12) + (cc << 7) + pp;
            }
            float* op = out + (size_t)orow * 256 + col0 + wc + fr;
#pragma unroll
            for (int j = 0; j < 4; j++)
                op[j * 16] = acc[i][j][r];
        }
    }
}

extern "C" void kernel_launch(void* const* d_in, const int* in_sizes, int n_in,
                              void* d_out, int out_size, void* d_ws, size_t ws_size,
                              hipStream_t stream)
{
    (void)in_sizes; (void)n_in; (void)out_size; (void)ws_size;
    const float* qz     = (const float*)d_in[0];
    const float* mask_t = (const float*)d_in[1];
    const float* mask_c = (const float*)d_in[2];
    const float* u_time = (const float*)d_in[3];
    const float* v_time = (const float*)d_in[4];
    const float* u_chan = (const float*)d_in[5];
    const float* v_chan = (const float*)d_in[6];
    float* out = (float*)d_out;
    float* W = (float*)d_ws;

    float* quR_t = W;
    float* qvR_t = W + 8388608;
    float* quR_c = W + 16777216;
    float* qvR_c = W + 25165824;
    float* S     = W + 33554432;
    float* max_t = S;
    float* sum_t = S + 262144;
    float* max_c = S + 524288;
    float* sum_c = S + 786432;
    float* Mrow  = S + 1048576;
    float* Sinv  = S + 1310720;
    unsigned int* BP = (unsigned int*)(W + 35127296);
    unsigned short* GPt = (unsigned short*)quR_t;   // planar g1|g2 slices (alias)
    unsigned short* GPc = (unsigned short*)quR_c;

    dim3 blk(256);
    v7_prepB<<<dim3(16, 4), blk, 0, stream>>>(u_time, v_time, u_chan, v_chan, BP);
    v5_proj<<<dim3(512, 8), blk, 0, stream>>>(qz, u_time, v_time, quR_t, qvR_t, 0, 127);
    v5_proj<<<dim3(512, 8), blk, 0, stream>>>(qz, u_chan, v_chan, quR_c, qvR_c, 1, 31);
    v5_stats_t<<<2048, blk, 0, stream>>>(quR_t, qvR_t, mask_t, max_t, sum_t);
    v5_stats_c<<<1024, blk, 0, stream>>>(quR_c, qvR_c, mask_c, max_c, sum_c);
    v5_merge<<<1024, blk, 0, stream>>>(max_t, sum_t, max_c, sum_c, Mrow, Sinv);
    v8_G_t<<<2048, blk, 0, stream>>>(quR_t, qvR_t, mask_t, Mrow, Sinv, GPt);
    v8_outgemm<<<dim3(256, 2), blk, 0, stream>>>(GPt, BP, BP + 65536, out, 0);
    v8_G_c<<<1024, blk, 0, stream>>>(quR_c, qvR_c, mask_c, Mrow, Sinv, GPc);
    v8_outgemm<<<dim3(256, 2), blk, 0, stream>>>(GPc, BP + 131072, BP + 196608, out + 8388608, 1);
}

// Round 16
// 526.235 us; speedup vs baseline: 1.5892x; 1.3102x over previous
//
#include <hip/hip_runtime.h>
#include <hip/hip_bf16.h>
#include <math.h>

// B=8 C=32 P=128 D=256 H=8 R=32; time: 256 seqs x 128; chan: 1024 seqs x 32.
// v10: v9 + proj moved to MFMA (4-term hi/lo split of qz and u/v for
//      fp32-equivalent precision; RoPE fused into the register epilogue).
//      prepB also emits elementwise-packed natural-layout u/v planes (PP).
#define LOG2T_16 0.8304820237218406f  // log2(10000)/16

typedef __attribute__((ext_vector_type(8))) short short8;
typedef __attribute__((ext_vector_type(4))) float f32x4;

#define PERM_LO 0x05040100u  // [x.b0,x.b1,y.b0,y.b1] from perm(y,x,sel)
#define PERM_HI 0x07060302u  // [x.b2,x.b3,y.b2,y.b3]

__device__ __forceinline__ float bf2f(unsigned short u) {
    union { float f; unsigned int i; } x; x.i = ((unsigned int)u) << 16; return x.f;
}
__device__ __forceinline__ unsigned short f2b(float f) {
    __hip_bfloat16 h = __float2bfloat16(f);
    union { __hip_bfloat16 h; unsigned short u; } x; x.h = h; return x.u;
}

__device__ __forceinline__ float v5_dot32(const float* qurow, const float* row) {
    float dot = 0.f;
#pragma unroll
    for (int q = 0; q < 8; q++) {
        float4 x = *(const float4*)(row + q * 4);
        dot = fmaf(qurow[q * 4 + 0], x.x, dot);
        dot = fmaf(qurow[q * 4 + 1], x.y, dot);
        dot = fmaf(qurow[q * 4 + 2], x.z, dot);
        dot = fmaf(qurow[q * 4 + 3], x.w, dot);
    }
    return dot;
}

__device__ __forceinline__ void v5_fma32(float p_, const float* row, float* acc) {
#pragma unroll
    for (int q = 0; q < 8; q++) {
        float4 x = *(const float4*)(row + q * 4);
        float xs[4] = {x.x, x.y, x.z, x.w};
#pragma unroll
        for (int i = 0; i < 4; i++)
            acc[q * 4 + i] = fmaf(p_, xs[i], acc[q * 4 + i]);
    }
}

// ---------- K0 v10: prep B planes: transposed packed (Bp, for outgemm) AND
// elementwise packed natural-layout (Pp, for proj MFMA B-operand) ----------
__global__ __launch_bounds__(256) void v10_prepB(
    const float* __restrict__ u_t, const float* __restrict__ v_t,
    const float* __restrict__ u_c, const float* __restrict__ v_c,
    unsigned int* __restrict__ Bp, unsigned int* __restrict__ Pp)
{
    __shared__ float Ts[64][65];
    const int mtx = blockIdx.y;
    const float* src = (mtx == 0) ? u_t : (mtx == 1) ? v_t : (mtx == 2) ? u_c : v_c;
    unsigned int* dst  = Bp + (size_t)mtx * 65536;
    unsigned int* pdst = Pp + (size_t)mtx * 65536;
    const int k0 = (blockIdx.x >> 2) * 64;
    const int c0 = (blockIdx.x & 3) * 64;
    const int tid = threadIdx.x;
    const int lr = tid >> 2;              // 0..63
    const int lc0 = (tid & 3) * 16;
    float av[16];
#pragma unroll
    for (int q = 0; q < 4; q++) {
        float4 x = *(const float4*)(src + (size_t)(k0 + lr) * 256 + c0 + lc0 + q * 4);
        *(float4*)&av[q * 4] = x;
        *(float4*)&Ts[lr][lc0 + q * 4] = x;     // Ts[k_local][c_local]
    }
    // elementwise packed (natural [row][col] layout) for proj
#pragma unroll
    for (int q = 0; q < 4; q++) {
        unsigned int w[4];
#pragma unroll
        for (int e = 0; e < 4; e++) {
            float x = av[q * 4 + e];
            unsigned short hi = f2b(x);
            unsigned short lo = f2b(x - bf2f(hi));
            w[e] = (unsigned int)hi | ((unsigned int)lo << 16);
        }
        *(uint4*)(pdst + (size_t)(k0 + lr) * 256 + c0 + lc0 + q * 4) =
            make_uint4(w[0], w[1], w[2], w[3]);
    }
    __syncthreads();
#pragma unroll
    for (int q = 0; q < 4; q++) {
        unsigned int w[4];
#pragma unroll
        for (int e = 0; e < 4; e++) {
            float x = Ts[lc0 + q * 4 + e][lr];
            unsigned short hi = f2b(x);
            unsigned short lo = f2b(x - bf2f(hi));
            w[e] = (unsigned int)hi | ((unsigned int)lo << 16);
        }
        *(uint4*)(dst + (size_t)(c0 + lr) * 256 + k0 + lc0 + q * 4) =
            make_uint4(w[0], w[1], w[2], w[3]);
    }
}

// ---------- K1 v10: proj via MFMA. [qu|qv] = RoPE(qz @ [u;v]^T).
// A = qz hi/lo split in-kernel; B = packed Pp planes; 4-term product. ----------
__global__ __launch_bounds__(256) void v10_proj(
    const float* __restrict__ qz,
    const unsigned int* __restrict__ Pu, const unsigned int* __restrict__ Pv,
    float* __restrict__ qu_rot, float* __restrict__ qv_rot, int chan, int posmask)
{
    __shared__ __align__(16) unsigned short Ah[128][40];
    __shared__ __align__(16) unsigned short Al[128][40];
    __shared__ __align__(16) unsigned short Bh[128][40];
    __shared__ __align__(16) unsigned short Bl[128][40];
    const int row0 = blockIdx.x * 128;
    const int col0 = blockIdx.y * 128;           // 0,128 -> u ; 256,384 -> v
    const unsigned int* Bsrc = (col0 < 256) ? Pu : Pv;
    float* Cout = (col0 < 256) ? qu_rot : qv_rot;
    const int ccol0 = col0 & 255;
    const int tid = threadIdx.x;
    const int sr = tid >> 1;                     // staging row/col 0..127
    const int sk = (tid & 1) * 16;               // staging k offset {0,16}
    const int wv = tid >> 6;
    const int lane = tid & 63;
    const int wr = (wv >> 1) * 64, wc = (wv & 1) * 64;
    const int fr = lane & 15;
    const int fk = (lane >> 4) * 8;

    int arow = row0 + sr;
    if (chan) {
        int b = arow >> 12, p = (arow >> 5) & 127, c = arow & 31;
        arow = (b * 32 + c) * 128 + p;
    }
    const float* aptr = qz + (size_t)arow * 256 + sk;
    const unsigned int* bptr = Bsrc + (size_t)(ccol0 + sr) * 256 + sk;

    f32x4 acc[4][4] = {};

    for (int k0 = 0; k0 < 256; k0 += 32) {
        // stage A: fp32 -> hi/lo bf16 planes
        float av[16];
#pragma unroll
        for (int q = 0; q < 4; q++)
            *(float4*)&av[q * 4] = *(const float4*)(aptr + k0 + q * 4);
        unsigned int wh[8], wl[8];
#pragma unroll
        for (int e = 0; e < 8; e++) {
            unsigned short h0 = f2b(av[2 * e]), h1 = f2b(av[2 * e + 1]);
            unsigned short l0 = f2b(av[2 * e] - bf2f(h0));
            unsigned short l1 = f2b(av[2 * e + 1] - bf2f(h1));
            wh[e] = (unsigned int)h0 | ((unsigned int)h1 << 16);
            wl[e] = (unsigned int)l0 | ((unsigned int)l1 << 16);
        }
        *(uint4*)&Ah[sr][sk]     = make_uint4(wh[0], wh[1], wh[2], wh[3]);
        *(uint4*)&Ah[sr][sk + 8] = make_uint4(wh[4], wh[5], wh[6], wh[7]);
        *(uint4*)&Al[sr][sk]     = make_uint4(wl[0], wl[1], wl[2], wl[3]);
        *(uint4*)&Al[sr][sk + 8] = make_uint4(wl[4], wl[5], wl[6], wl[7]);
        // stage B: packed hi|lo -> split planes via perm
#pragma unroll
        for (int q = 0; q < 4; q++) {
            uint4 w = *(const uint4*)(bptr + k0 + q * 4);
            *(uint2*)&Bh[sr][sk + q * 4] = make_uint2(
                __builtin_amdgcn_perm(w.y, w.x, PERM_LO),
                __builtin_amdgcn_perm(w.w, w.z, PERM_LO));
            *(uint2*)&Bl[sr][sk + q * 4] = make_uint2(
                __builtin_amdgcn_perm(w.y, w.x, PERM_HI),
                __builtin_amdgcn_perm(w.w, w.z, PERM_HI));
        }
        __syncthreads();
        short8 ah[4], al[4];
#pragma unroll
        for (int i = 0; i < 4; i++) {
            ah[i] = *(const short8*)&Ah[wr + i * 16 + fr][fk];
            al[i] = *(const short8*)&Al[wr + i * 16 + fr][fk];
        }
#pragma unroll
        for (int j = 0; j < 4; j++) {
            const int bc = wc + j * 16 + fr;
            short8 bh = *(const short8*)&Bh[bc][fk];
            short8 bl = *(const short8*)&Bl[bc][fk];
#pragma unroll
            for (int i = 0; i < 4; i++) {
                acc[i][j] = __builtin_amdgcn_mfma_f32_16x16x32_bf16(ah[i], bh, acc[i][j], 0, 0, 0);
                acc[i][j] = __builtin_amdgcn_mfma_f32_16x16x32_bf16(ah[i], bl, acc[i][j], 0, 0, 0);
                acc[i][j] = __builtin_amdgcn_mfma_f32_16x16x32_bf16(al[i], bh, acc[i][j], 0, 0, 0);
                acc[i][j] = __builtin_amdgcn_mfma_f32_16x16x32_bf16(al[i], bl, acc[i][j], 0, 0, 0);
            }
        }
        __syncthreads();
    }
    // epilogue: RoPE in registers. Fragments j=2t and 2t+1 give the (col, col+16)
    // pair for the same (row, fr) on the same lane; pos from the LOGICAL row mr.
    const float fscale = exp2f(-(float)fr * LOG2T_16);
#pragma unroll
    for (int i = 0; i < 4; i++) {
#pragma unroll
        for (int r = 0; r < 4; r++) {
            int mr = row0 + wr + i * 16 + (lane >> 4) * 4 + r;
            float pos = (float)(mr & posmask);
            float sn, cs;
            sincosf(pos * fscale, &sn, &cs);        // precise: pre-softmax path
            float* op = Cout + (size_t)mr * 256 + ccol0 + wc + fr;
#pragma unroll
            for (int t = 0; t < 2; t++) {
                float x = acc[i][2 * t][r], y = acc[i][2 * t + 1][r];
                op[t * 32]      = x * cs - y * sn;   // apply
                op[t * 32 + 16] = y * cs + x * sn;
            }
        }
    }
}

// ---------- K2 v9: time-path stats; XCD co-location (n = bid&255) ----------
__global__ __launch_bounds__(256) void v5_stats_t(
    const float* __restrict__ quR, const float* __restrict__ qvR,
    const float* __restrict__ mask, float* __restrict__ omax, float* __restrict__ osum)
{
    __shared__ float Qv[128][36];
    const int bid = blockIdx.x;
    const int n = bid & 255, h = bid >> 8;      // same-n blocks -> same XCD
    const int b = n >> 5, c = n & 31;
    const int tid = threadIdx.x;
    for (int idx = tid * 4; idx < 4096; idx += 1024) {
        int s = idx >> 5, r = idx & 31;
        *(float4*)&Qv[s][r] = *(const float4*)(qvR + ((size_t)(n * 128 + s)) * 256 + h * 32 + r);
    }
    const int s = tid >> 1, toff = (tid & 1) * 64;
    float qurow[32];
    const float* qptr = quR + ((size_t)(n * 128 + s)) * 256 + h * 32;
#pragma unroll
    for (int q = 0; q < 8; q++) {
        float4 x = *(const float4*)(qptr + q * 4);
        qurow[q * 4 + 0] = x.x; qurow[q * 4 + 1] = x.y; qurow[q * 4 + 2] = x.z; qurow[q * 4 + 3] = x.w;
    }
    __syncthreads();
    const float* mrow = mask + (size_t)n * 16384 + s * 128 + toff;
    float mx = -1e30f, sm = 0.f;
#pragma unroll 4
    for (int t = 0; t < 64; t++) {
        float dot = v5_dot32(qurow, &Qv[toff + t][0]);
        float vv = 256.f * (dot + mrow[t]);
        float nm = fmaxf(mx, vv);
        sm = sm * __expf(mx - nm) + __expf(vv - nm);
        mx = nm;
    }
    float omx = __shfl_xor(mx, 1);
    float osm = __shfl_xor(sm, 1);
    float fm = fmaxf(mx, omx);
    float fs = sm * __expf(mx - fm) + osm * __expf(omx - fm);
    if ((tid & 1) == 0) {
        int idx = ((b * 8 + h) * 32 + c) * 128 + s;
        omax[idx] = fm; osum[idx] = fs;
    }
}

// ---------- K3: chan-path partial softmax stats (unchanged) ----------
__global__ __launch_bounds__(256) void v5_stats_c(
    const float* __restrict__ quR, const float* __restrict__ qvR,
    const float* __restrict__ mask, float* __restrict__ omax, float* __restrict__ osum)
{
    __shared__ float Qv[32][260];
    const int m = blockIdx.x;                   // b*128 + p
    const int b = m >> 7, p = m & 127;
    const int tid = threadIdx.x;
    for (int idx = tid * 4; idx < 8192; idx += 1024) {
        int sc = idx >> 8, dd = idx & 255;
        *(float4*)&Qv[sc][dd] = *(const float4*)(qvR + ((size_t)m * 32 + sc) * 256 + dd);
    }
    const int h = tid >> 5, sc = tid & 31;
    float qurow[32];
    const float* qptr = quR + ((size_t)m * 32 + sc) * 256 + h * 32;
#pragma unroll
    for (int q = 0; q < 8; q++) {
        float4 x = *(const float4*)(qptr + q * 4);
        qurow[q * 4 + 0] = x.x; qurow[q * 4 + 1] = x.y; qurow[q * 4 + 2] = x.z; qurow[q * 4 + 3] = x.w;
    }
    __syncthreads();
    const float* mrow = mask + (size_t)m * 1024 + sc * 32;
    float mx = -1e30f, sm = 0.f;
#pragma unroll 4
    for (int t = 0; t < 32; t++) {
        float dot = v5_dot32(qurow, &Qv[t][h * 32]);
        float vv = 256.f * (dot + mrow[t]);
        float nm = fmaxf(mx, vv);
        sm = sm * __expf(mx - nm) + __expf(vv - nm);
        mx = nm;
    }
    int idx = ((b * 8 + h) * 32 + sc) * 128 + p;
    omax[idx] = mx; osum[idx] = sm;
}

// ---------- K4: merge joint-softmax stats (unchanged) ----------
__global__ __launch_bounds__(256) void v5_merge(
    const float* __restrict__ mt, const float* __restrict__ st,
    const float* __restrict__ mc, const float* __restrict__ sc,
    float* __restrict__ Mo, float* __restrict__ So)
{
    int i = blockIdx.x * 256 + threadIdx.x;
    float a = mt[i], b = mc[i];
    float mx = fmaxf(a, b);
    float s = st[i] * __expf(a - mx) + sc[i] * __expf(b - mx);
    Mo[i] = mx;
    So[i] = 1.f / s;
}

// ---------- K5 v9: time-path G with MFMA PV; XCD co-location (n = bid&255) ----------
__global__ __launch_bounds__(256) void v8_G_t(
    const float* quR, const float* qvR,
    const float* __restrict__ mask, const float* __restrict__ Mr, const float* __restrict__ Sv,
    unsigned short* gpl)
{
    __shared__ __align__(16) unsigned short Pm[16384];  // [128][128] XOR-swizzled
    __shared__ __align__(16) float Qv[128][36];         // fp32 (P phase); then QT u16 planes
    unsigned short* QT = (unsigned short*)&Qv[0][0];    // hi[32][128] @0, lo @4096
    const int bid = blockIdx.x;
    const int n = bid & 255, h = bid >> 8;      // same-n blocks -> same XCD
    const int b = n >> 5, c = n & 31;
    const int tid = threadIdx.x;
    const int lane = tid & 63, wv = tid >> 6;
    const int fr = lane & 15, kgl = lane >> 4;

    // phase 0: stage Qv fp32
    for (int idx = tid * 4; idx < 4096; idx += 1024) {
        int s = idx >> 5, r = idx & 31;
        *(float4*)&Qv[s][r] = *(const float4*)(qvR + ((size_t)(n * 128 + s)) * 256 + h * 32 + r);
    }
    // phase 1: P (scalar fp32 QK^T + exp) -> Pm swizzled
    {
        const int s = tid >> 1, toff = (tid & 1) * 64;
        float qurow[32];
        const float* qptr = quR + ((size_t)(n * 128 + s)) * 256 + h * 32;
#pragma unroll
        for (int q = 0; q < 8; q++) {
            float4 x = *(const float4*)(qptr + q * 4);
            qurow[q * 4 + 0] = x.x; qurow[q * 4 + 1] = x.y; qurow[q * 4 + 2] = x.z; qurow[q * 4 + 3] = x.w;
        }
        __syncthreads();
        const int rowidx = ((b * 8 + h) * 32 + c) * 128 + s;
        const float Mx = Mr[rowidx];
        const float Si = Sv[rowidx];
        const float* mrow = mask + (size_t)n * 16384 + s * 128 + toff;
#pragma unroll 4
        for (int t = 0; t < 64; t++) {
            float dot = v5_dot32(qurow, &Qv[toff + t][0]);
            float pv = __expf(256.f * (dot + mrow[t]) - Mx) * Si;
            int tg = toff + t;
            int ct = (((tg >> 3) ^ (s & 15)) << 3) | (tg & 7);
            Pm[s * 128 + ct] = f2b(pv);
        }
    }
    __syncthreads();
    // phase 2: build QvT hi/lo (transposed, swizzled) from GLOBAL qvR; overwrites Qv
    {
        const int t = tid >> 1, rh = (tid & 1) * 16;
        const float* src = qvR + ((size_t)(n * 128 + t)) * 256 + h * 32 + rh;
        float v[16];
#pragma unroll
        for (int q = 0; q < 4; q++)
            *(float4*)&v[q * 4] = *(const float4*)(src + q * 4);
#pragma unroll
        for (int i = 0; i < 16; i++) {
            int r = rh + i;
            unsigned short hi = f2b(v[i]);
            unsigned short lo = f2b(v[i] - bf2f(hi));
            int ct = (((t >> 3) ^ (r & 15)) << 3) | (t & 7);
            QT[r * 128 + ct] = hi;
            QT[4096 + r * 128 + ct] = lo;
        }
    }
    __syncthreads();
    // phase 3: g1 = P @ Qv (MFMA), rotate (apply_o, pos=s) -> regs
    unsigned int g1h[8];
    {
        f32x4 acc[2][2] = {};
#pragma unroll
        for (int kw = 0; kw < 4; kw++) {
            short8 a[2];
#pragma unroll
            for (int i = 0; i < 2; i++) {
                int row = wv * 32 + i * 16 + fr;
                a[i] = *(const short8*)&Pm[row * 128 + (((kw * 4 + kgl) ^ (row & 15)) << 3)];
            }
            short8 bh[2], bl[2];
#pragma unroll
            for (int j = 0; j < 2; j++) {
                int r = j * 16 + fr;
                int off = r * 128 + (((kw * 4 + kgl) ^ (r & 15)) << 3);
                bh[j] = *(const short8*)&QT[off];
                bl[j] = *(const short8*)&QT[4096 + off];
            }
#pragma unroll
            for (int i = 0; i < 2; i++)
#pragma unroll
                for (int j = 0; j < 2; j++) {
                    acc[i][j] = __builtin_amdgcn_mfma_f32_16x16x32_bf16(a[i], bh[j], acc[i][j], 0, 0, 0);
                    acc[i][j] = __builtin_amdgcn_mfma_f32_16x16x32_bf16(a[i], bl[j], acc[i][j], 0, 0, 0);
                }
        }
#pragma unroll
        for (int i = 0; i < 2; i++)
#pragma unroll
            for (int reg = 0; reg < 4; reg++) {
                int s = wv * 32 + i * 16 + kgl * 4 + reg;
                float ang = (float)s * exp2f(-(float)fr * LOG2T_16);
                float sn, cs;
                __sincosf(ang, &sn, &cs);
                float x = acc[i][0][reg], y = acc[i][1][reg];
                g1h[i * 4 + reg] = (unsigned int)f2b(x * cs + y * sn)
                                 | ((unsigned int)f2b(y * cs - x * sn) << 16);
            }
    }
    __syncthreads();
    // phase 4: build QoT hi/lo = R(-2theta)*quR transposed (LAST quR reads)
    {
        const int t = tid >> 1, jh = (tid & 1) * 8;
        const float* base = quR + ((size_t)(n * 128 + t)) * 256 + h * 32;
        float aa[8], bb[8];
        *(float4*)&aa[0] = *(const float4*)(base + jh);
        *(float4*)&aa[4] = *(const float4*)(base + jh + 4);
        *(float4*)&bb[0] = *(const float4*)(base + jh + 16);
        *(float4*)&bb[4] = *(const float4*)(base + jh + 20);
#pragma unroll
        for (int i = 0; i < 8; i++) {
            int j = jh + i;
            float ang = 2.f * (float)t * exp2f(-(float)j * LOG2T_16);
            float s2, c2;
            __sincosf(ang, &s2, &c2);
            float o1 = aa[i] * c2 + bb[i] * s2;   // col j
            float o2 = bb[i] * c2 - aa[i] * s2;   // col j+16
            int ct1 = (((t >> 3) ^ (j & 15)) << 3) | (t & 7);
            unsigned short h1 = f2b(o1);
            QT[j * 128 + ct1] = h1;
            QT[4096 + j * 128 + ct1] = f2b(o1 - bf2f(h1));
            int r2 = j + 16;
            int ct2 = (((t >> 3) ^ (r2 & 15)) << 3) | (t & 7);
            unsigned short h2 = f2b(o2);
            QT[r2 * 128 + ct2] = h2;
            QT[4096 + r2 * 128 + ct2] = f2b(o2 - bf2f(h2));
        }
    }
    __syncthreads();
    // phase 5: g2T = QoT @ P (B = Pm columns via swizzle), rotate (apply) -> regs
    unsigned int g2h[8];
    {
        f32x4 acc[2][2] = {};   // [r-tile][s-tile-local]
#pragma unroll
        for (int kw = 0; kw < 4; kw++) {
            short8 ah[2], al[2];
#pragma unroll
            for (int i = 0; i < 2; i++) {
                int r = i * 16 + fr;
                int off = r * 128 + (((kw * 4 + kgl) ^ (r & 15)) << 3);
                ah[i] = *(const short8*)&QT[off];
                al[i] = *(const short8*)&QT[4096 + off];
            }
            short8 bfr[2];
#pragma unroll
            for (int jj = 0; jj < 2; jj++) {
                int scol = (2 * wv + jj) * 16 + fr;
#pragma unroll
                for (int j = 0; j < 8; j++) {
                    int t = kw * 32 + kgl * 8 + j;
                    int ct = (((scol >> 3) ^ (t & 15)) << 3) | (scol & 7);
                    bfr[jj][j] = (short)Pm[t * 128 + ct];
                }
            }
#pragma unroll
            for (int i = 0; i < 2; i++)
#pragma unroll
                for (int jj = 0; jj < 2; jj++) {
                    acc[i][jj] = __builtin_amdgcn_mfma_f32_16x16x32_bf16(ah[i], bfr[jj], acc[i][jj], 0, 0, 0);
                    acc[i][jj] = __builtin_amdgcn_mfma_f32_16x16x32_bf16(al[i], bfr[jj], acc[i][jj], 0, 0, 0);
                }
        }
#pragma unroll
        for (int jj = 0; jj < 2; jj++)
#pragma unroll
            for (int reg = 0; reg < 4; reg++) {
                int sv = (2 * wv + jj) * 16 + fr;
                int r = kgl * 4 + reg;
                float ang = (float)sv * exp2f(-(float)r * LOG2T_16);
                float sn, cs;
                __sincosf(ang, &sn, &cs);
                float x = acc[0][jj][reg], y = acc[1][jj][reg];
                g2h[jj * 4 + reg] = (unsigned int)f2b(x * cs - y * sn)
                                  | ((unsigned int)f2b(y * cs + x * sn) << 16);
            }
    }
    __syncthreads();
    // phase 6: bounce rotated g1/g2 into Pm region ([s][32] u16 each)
    {
#pragma unroll
        for (int i = 0; i < 2; i++)
#pragma unroll
            for (int reg = 0; reg < 4; reg++) {
                int s = wv * 32 + i * 16 + kgl * 4 + reg;
                unsigned int w = g1h[i * 4 + reg];
                Pm[s * 32 + fr] = (unsigned short)w;
                Pm[s * 32 + fr + 16] = (unsigned short)(w >> 16);
            }
#pragma unroll
        for (int jj = 0; jj < 2; jj++)
#pragma unroll
            for (int reg = 0; reg < 4; reg++) {
                int s = (2 * wv + jj) * 16 + fr;
                int r = kgl * 4 + reg;
                unsigned int w = g2h[jj * 4 + reg];
                Pm[4096 + s * 32 + r] = (unsigned short)w;
                Pm[4096 + s * 32 + r + 16] = (unsigned short)(w >> 16);
            }
    }
    __syncthreads();
    // phase 7: coalesced planar stores (g1 at slice+0, g2 at slice+32 ushorts)
    {
        const int s = tid >> 1, rh = (tid & 1) * 16;
        size_t baseu = ((size_t)(n * 128 + s)) * 512 + h * 64 + rh;
        *(uint4*)(gpl + baseu)      = *(const uint4*)&Pm[s * 32 + rh];
        *(uint4*)(gpl + baseu + 8)  = *(const uint4*)&Pm[s * 32 + rh + 8];
        *(uint4*)(gpl + baseu + 32) = *(const uint4*)&Pm[4096 + s * 32 + rh];
        *(uint4*)(gpl + baseu + 40) = *(const uint4*)&Pm[4096 + s * 32 + rh + 8];
    }
}

// ---------- K6 v8: chan-path G, scalar (unchanged), planar stores ----------
__global__ __launch_bounds__(256) void v8_G_c(
    const float* quR, const float* qvR,
    const float* __restrict__ mask, const float* __restrict__ Mr, const float* __restrict__ Sv,
    unsigned short* gpl)
{
    __shared__ float Qv[32][260];
    __shared__ unsigned short Pm[8][32][34];
    const int m = blockIdx.x;
    const int b = m >> 7, p = m & 127;
    const int tid = threadIdx.x;
    for (int idx = tid * 4; idx < 8192; idx += 1024) {
        int sc = idx >> 8, dd = idx & 255;
        *(float4*)&Qv[sc][dd] = *(const float4*)(qvR + ((size_t)m * 32 + sc) * 256 + dd);
    }
    const int h = tid >> 5, sc = tid & 31;
    {
        float qurow[32];
        const float* qptr = quR + ((size_t)m * 32 + sc) * 256 + h * 32;
#pragma unroll
        for (int q = 0; q < 8; q++) {
            float4 x = *(const float4*)(qptr + q * 4);
            qurow[q * 4 + 0] = x.x; qurow[q * 4 + 1] = x.y; qurow[q * 4 + 2] = x.z; qurow[q * 4 + 3] = x.w;
        }
        __syncthreads();
        const int rowidx = ((b * 8 + h) * 32 + sc) * 128 + p;
        const float Mx = Mr[rowidx], Si = Sv[rowidx];
        const float* mrow = mask + (size_t)m * 1024 + sc * 32;
#pragma unroll 4
        for (int t = 0; t < 32; t++) {
            float dot = v5_dot32(qurow, &Qv[t][h * 32]);
            float pv = __expf(256.f * (dot + mrow[t]) - Mx) * Si;
            Pm[h][t][sc] = f2b(pv);
        }
    }
    __syncthreads();
    float a[32] = {};
#pragma unroll 4
    for (int t = 0; t < 32; t++) {
        float p_ = bf2f(Pm[h][t][sc]);
        v5_fma32(p_, &Qv[t][h * 32], a);
    }
    float cs[16], sn[16];
#pragma unroll
    for (int i = 0; i < 16; i++) {
        float ang = (float)sc * exp2f(-(float)i * LOG2T_16);
        __sincosf(ang, &sn[i], &cs[i]);
    }
    unsigned int g1p[8], g1q[8];
#pragma unroll
    for (int j = 0; j < 8; j++) {
        int i0 = 2 * j, i1 = 2 * j + 1;
        float x0 = a[i0], y0 = a[16 + i0], x1 = a[i1], y1 = a[16 + i1];
        g1p[j] = (unsigned int)f2b(x0 * cs[i0] + y0 * sn[i0])
               | ((unsigned int)f2b(x1 * cs[i1] + y1 * sn[i1]) << 16);
        g1q[j] = (unsigned int)f2b(y0 * cs[i0] - x0 * sn[i0])
               | ((unsigned int)f2b(y1 * cs[i1] - x1 * sn[i1]) << 16);
    }
    __syncthreads();
    // restage Qo (LAST quR reads, before any gpl write)
    for (int idx = tid * 4; idx < 4096; idx += 1024) {
        int row = idx >> 7, rem = idx & 127;
        int h2 = rem >> 4, j0 = rem & 15;
        const float* base = quR + ((size_t)m * 32 + row) * 256 + h2 * 32;
        float4 a4 = *(const float4*)(base + j0);
        float4 b4 = *(const float4*)(base + j0 + 16);
        float aa[4] = {a4.x, a4.y, a4.z, a4.w};
        float bb[4] = {b4.x, b4.y, b4.z, b4.w};
        float o1[4], o2[4];
#pragma unroll
        for (int i = 0; i < 4; i++) {
            float ang = 2.f * (float)row * exp2f(-(float)(j0 + i) * LOG2T_16);
            float s2, c2;
            __sincosf(ang, &s2, &c2);
            o1[i] = aa[i] * c2 + bb[i] * s2;
            o2[i] = bb[i] * c2 - aa[i] * s2;
        }
        *(float4*)&Qv[row][h2 * 32 + j0]      = make_float4(o1[0], o1[1], o1[2], o1[3]);
        *(float4*)&Qv[row][h2 * 32 + j0 + 16] = make_float4(o2[0], o2[1], o2[2], o2[3]);
    }
    __syncthreads();
#pragma unroll
    for (int i = 0; i < 32; i++) a[i] = 0.f;
#pragma unroll 4
    for (int t = 0; t < 32; t++) {
        float p_ = bf2f(Pm[h][sc][t]);
        v5_fma32(p_, &Qv[t][h * 32], a);
    }
    // planar stores: g1 uints [0,16), g2 uints [16,32) of the (row,h) slice
    unsigned int* gpu = (unsigned int*)gpl;
    size_t ub = ((size_t)m * 32 + sc) * 256 + h * 32;
    *(uint4*)(gpu + ub)      = make_uint4(g1p[0], g1p[1], g1p[2], g1p[3]);
    *(uint4*)(gpu + ub + 4)  = make_uint4(g1p[4], g1p[5], g1p[6], g1p[7]);
    *(uint4*)(gpu + ub + 8)  = make_uint4(g1q[0], g1q[1], g1q[2], g1q[3]);
    *(uint4*)(gpu + ub + 12) = make_uint4(g1q[4], g1q[5], g1q[6], g1q[7]);
    unsigned int p2[8], q2[8];
#pragma unroll
    for (int j = 0; j < 8; j++) {
        int i0 = 2 * j, i1 = 2 * j + 1;
        p2[j] = (unsigned int)f2b(a[i0] * cs[i0] - a[16 + i0] * sn[i0])
              | ((unsigned int)f2b(a[i1] * cs[i1] - a[16 + i1] * sn[i1]) << 16);
        q2[j] = (unsigned int)f2b(a[16 + i0] * cs[i0] + a[i0] * sn[i0])
              | ((unsigned int)f2b(a[16 + i1] * cs[i1] + a[i1] * sn[i1]) << 16);
    }
    *(uint4*)(gpu + ub + 16) = make_uint4(p2[0], p2[1], p2[2], p2[3]);
    *(uint4*)(gpu + ub + 20) = make_uint4(p2[4], p2[5], p2[6], p2[7]);
    *(uint4*)(gpu + ub + 24) = make_uint4(q2[0], q2[1], q2[2], q2[3]);
    *(uint4*)(gpu + ub + 28) = make_uint4(q2[4], q2[5], q2[6], q2[7]);
}

// ---------- K7 v8: outgemm, planar A (g1/g2 slices), split-B MFMA (unchanged) ----------
__global__ __launch_bounds__(256) void v8_outgemm(
    const unsigned short* __restrict__ gpl,  // planar slices: g1 [0,32), g2 [32,64) per (row,h)
    const unsigned int* __restrict__ Bu,
    const unsigned int* __restrict__ Bv,
    float* __restrict__ out, int remap)
{
    __shared__ __align__(16) unsigned short A1[128][40];
    __shared__ __align__(16) unsigned short A2[128][40];
    __shared__ __align__(16) unsigned short Bh[2][128][40];
    __shared__ __align__(16) unsigned short Bl[2][128][40];
    const int row0 = blockIdx.x * 128;
    const int col0 = blockIdx.y * 128;
    const int tid = threadIdx.x;
    const int sr = tid >> 1;
    const int sk = (tid & 1) * 16;
    const int wv = tid >> 6;
    const int lane = tid & 63;
    const int wr = (wv >> 1) * 64, wc = (wv & 1) * 64;
    const int fr = lane & 15;
    const int fk = (lane >> 4) * 8;

    const unsigned int* uptr = Bu + (size_t)(col0 + sr) * 256 + sk;
    const unsigned int* vptr = Bv + (size_t)(col0 + sr) * 256 + sk;

    f32x4 acc[4][4] = {};

    for (int k0 = 0; k0 < 256; k0 += 32) {
        int kb = k0 + sk;
        const unsigned short* ap = gpl + (size_t)(row0 + sr) * 512 + ((kb >> 5) << 6) + (kb & 31);
        *(uint4*)&A1[sr][sk]     = *(const uint4*)ap;
        *(uint4*)&A1[sr][sk + 8] = *(const uint4*)(ap + 8);
        *(uint4*)&A2[sr][sk]     = *(const uint4*)(ap + 32);
        *(uint4*)&A2[sr][sk + 8] = *(const uint4*)(ap + 40);
#pragma unroll
        for (int q = 0; q < 4; q++) {
            uint4 wU = *(const uint4*)(uptr + k0 + q * 4);
            *(uint2*)&Bh[0][sr][sk + q * 4] = make_uint2(
                __builtin_amdgcn_perm(wU.y, wU.x, PERM_LO),
                __builtin_amdgcn_perm(wU.w, wU.z, PERM_LO));
            *(uint2*)&Bl[0][sr][sk + q * 4] = make_uint2(
                __builtin_amdgcn_perm(wU.y, wU.x, PERM_HI),
                __builtin_amdgcn_perm(wU.w, wU.z, PERM_HI));
            uint4 wV = *(const uint4*)(vptr + k0 + q * 4);
            *(uint2*)&Bh[1][sr][sk + q * 4] = make_uint2(
                __builtin_amdgcn_perm(wV.y, wV.x, PERM_LO),
                __builtin_amdgcn_perm(wV.w, wV.z, PERM_LO));
            *(uint2*)&Bl[1][sr][sk + q * 4] = make_uint2(
                __builtin_amdgcn_perm(wV.y, wV.x, PERM_HI),
                __builtin_amdgcn_perm(wV.w, wV.z, PERM_HI));
        }
        __syncthreads();
        short8 a1[4], a2[4];
#pragma unroll
        for (int i = 0; i < 4; i++) {
            a1[i] = *(const short8*)&A1[wr + i * 16 + fr][fk];
            a2[i] = *(const short8*)&A2[wr + i * 16 + fr][fk];
        }
#pragma unroll
        for (int j = 0; j < 4; j++) {
            const int bc = wc + j * 16 + fr;
            short8 buh = *(const short8*)&Bh[0][bc][fk];
            short8 bul = *(const short8*)&Bl[0][bc][fk];
            short8 bvh = *(const short8*)&Bh[1][bc][fk];
            short8 bvl = *(const short8*)&Bl[1][bc][fk];
#pragma unroll
            for (int i = 0; i < 4; i++) {
                acc[i][j] = __builtin_amdgcn_mfma_f32_16x16x32_bf16(a1[i], buh, acc[i][j], 0, 0, 0);
                acc[i][j] = __builtin_amdgcn_mfma_f32_16x16x32_bf16(a1[i], bul, acc[i][j], 0, 0, 0);
                acc[i][j] = __builtin_amdgcn_mfma_f32_16x16x32_bf16(a2[i], bvh, acc[i][j], 0, 0, 0);
                acc[i][j] = __builtin_amdgcn_mfma_f32_16x16x32_bf16(a2[i], bvl, acc[i][j], 0, 0, 0);
            }
        }
        __syncthreads();
    }
#pragma unroll
    for (int i = 0; i < 4; i++) {
#pragma unroll
        for (int r = 0; r < 4; r++) {
            int mr = row0 + wr + i * 16 + (lane >> 4) * 4 + r;
            int orow = mr;
            if (remap) {
                int bb = mr >> 12, pp = (mr >> 5) & 127, cc = mr & 31;
                orow = (bb << 12) + (cc << 7) + pp;
            }
            float* op = out + (size_t)orow * 256 + col0 + wc + fr;
#pragma unroll
            for (int j = 0; j < 4; j++)
                op[j * 16] = acc[i][j][r];
        }
    }
}

extern "C" void kernel_launch(void* const* d_in, const int* in_sizes, int n_in,
                              void* d_out, int out_size, void* d_ws, size_t ws_size,
                              hipStream_t stream)
{
    (void)in_sizes; (void)n_in; (void)out_size; (void)ws_size;
    const float* qz     = (const float*)d_in[0];
    const float* mask_t = (const float*)d_in[1];
    const float* mask_c = (const float*)d_in[2];
    const float* u_time = (const float*)d_in[3];
    const float* v_time = (const float*)d_in[4];
    const float* u_chan = (const float*)d_in[5];
    const float* v_chan = (const float*)d_in[6];
    float* out = (float*)d_out;
    float* W = (float*)d_ws;

    float* quR_t = W;
    float* qvR_t = W + 8388608;
    float* quR_c = W + 16777216;
    float* qvR_c = W + 25165824;
    float* S     = W + 33554432;
    float* max_t = S;
    float* sum_t = S + 262144;
    float* max_c = S + 524288;
    float* sum_c = S + 786432;
    float* Mrow  = S + 1048576;
    float* Sinv  = S + 1310720;
    unsigned int* BP = (unsigned int*)(W + 35127296);   // transposed packed (4 x 65536)
    unsigned int* PP = BP + 262144;                     // natural packed (4 x 65536)
    unsigned short* GPt = (unsigned short*)quR_t;       // planar g1|g2 slices (alias)
    unsigned short* GPc = (unsigned short*)quR_c;

    dim3 blk(256);
    v10_prepB<<<dim3(16, 4), blk, 0, stream>>>(u_time, v_time, u_chan, v_chan, BP, PP);
    v10_proj<<<dim3(256, 4), blk, 0, stream>>>(qz, PP, PP + 65536, quR_t, qvR_t, 0, 127);
    v10_proj<<<dim3(256, 4), blk, 0, stream>>>(qz, PP + 131072, PP + 196608, quR_c, qvR_c, 1, 31);
    v5_stats_t<<<2048, blk, 0, stream>>>(quR_t, qvR_t, mask_t, max_t, sum_t);
    v5_stats_c<<<1024, blk, 0, stream>>>(quR_c, qvR_c, mask_c, max_c, sum_c);
    v5_merge<<<1024, blk, 0, stream>>>(max_t, sum_t, max_c, sum_c, Mrow, Sinv);
    v8_G_t<<<2048, blk, 0, stream>>>(quR_t, qvR_t, mask_t, Mrow, Sinv, GPt);
    v8_outgemm<<<dim3(256, 2), blk, 0, stream>>>(GPt, BP, BP + 65536, out, 0);
    v8_G_c<<<1024, blk, 0, stream>>>(quR_c, qvR_c, mask_c, Mrow, Sinv, GPc);
    v8_outgemm<<<dim3(256, 2), blk, 0, stream>>>(GPc, BP + 131072, BP + 196608, out + 8388608, 1);
}

// Round 17
// 444.868 us; speedup vs baseline: 1.8799x; 1.1829x over previous
//
#include <hip/hip_runtime.h>
#include <hip/hip_bf16.h>
#include <math.h>

// B=8 C=32 P=128 D=256 H=8 R=32; time: 256 seqs x 128; chan: 1024 seqs x 32.
// v11: v10 + MFMA QK^T in stats_t AND G_t (shared split/MFMA helpers so vv is
//      bit-identical in both -> softmax stays consistent). G_t unions the
//      split planes with Pm/QT (49KB LDS, 3 blocks/CU).
#define LOG2T_16 0.8304820237218406f  // log2(10000)/16

typedef __attribute__((ext_vector_type(8))) short short8;
typedef __attribute__((ext_vector_type(4))) float f32x4;

#define PERM_LO 0x05040100u
#define PERM_HI 0x07060302u

__device__ __forceinline__ float bf2f(unsigned short u) {
    union { float f; unsigned int i; } x; x.i = ((unsigned int)u) << 16; return x.f;
}
__device__ __forceinline__ unsigned short f2b(float f) {
    __hip_bfloat16 h = __float2bfloat16(f);
    union { __hip_bfloat16 h; unsigned short u; } x; x.h = h; return x.u;
}

__device__ __forceinline__ float v5_dot32(const float* qurow, const float* row) {
    float dot = 0.f;
#pragma unroll
    for (int q = 0; q < 8; q++) {
        float4 x = *(const float4*)(row + q * 4);
        dot = fmaf(qurow[q * 4 + 0], x.x, dot);
        dot = fmaf(qurow[q * 4 + 1], x.y, dot);
        dot = fmaf(qurow[q * 4 + 2], x.z, dot);
        dot = fmaf(qurow[q * 4 + 3], x.w, dot);
    }
    return dot;
}

__device__ __forceinline__ void v5_fma32(float p_, const float* row, float* acc) {
#pragma unroll
    for (int q = 0; q < 8; q++) {
        float4 x = *(const float4*)(row + q * 4);
        float xs[4] = {x.x, x.y, x.z, x.w};
#pragma unroll
        for (int i = 0; i < 4; i++)
            acc[q * 4 + i] = fmaf(p_, xs[i], acc[q * 4 + i]);
    }
}

// ---- shared QK^T helpers (MUST be identical in stats_t and G_t) ----
__device__ __forceinline__ void qk_stage_splits(
    const float* __restrict__ quR, const float* __restrict__ qvR,
    int n, int h, int tid,
    unsigned short* QUh, unsigned short* QUl,
    unsigned short* QVh, unsigned short* QVl)
{
    for (int idx = tid * 4; idx < 4096; idx += 1024) {
        int s = idx >> 5, r = idx & 31;
        size_t go = ((size_t)(n * 128 + s)) * 256 + h * 32 + r;
        float4 xu = *(const float4*)(quR + go);
        float4 xv = *(const float4*)(qvR + go);
        float us[4] = {xu.x, xu.y, xu.z, xu.w};
        float vs[4] = {xv.x, xv.y, xv.z, xv.w};
        unsigned short uh[4], ul[4], vh[4], vl[4];
#pragma unroll
        for (int e = 0; e < 4; e++) {
            uh[e] = f2b(us[e]); ul[e] = f2b(us[e] - bf2f(uh[e]));
            vh[e] = f2b(vs[e]); vl[e] = f2b(vs[e] - bf2f(vh[e]));
        }
        int lo = s * 40 + r;
        *(uint2*)&QUh[lo] = make_uint2((unsigned)uh[0] | ((unsigned)uh[1] << 16),
                                       (unsigned)uh[2] | ((unsigned)uh[3] << 16));
        *(uint2*)&QUl[lo] = make_uint2((unsigned)ul[0] | ((unsigned)ul[1] << 16),
                                       (unsigned)ul[2] | ((unsigned)ul[3] << 16));
        *(uint2*)&QVh[lo] = make_uint2((unsigned)vh[0] | ((unsigned)vh[1] << 16),
                                       (unsigned)vh[2] | ((unsigned)vh[3] << 16));
        *(uint2*)&QVl[lo] = make_uint2((unsigned)vl[0] | ((unsigned)vl[1] << 16),
                                       (unsigned)vl[2] | ((unsigned)vl[3] << 16));
    }
}

__device__ __forceinline__ void qk_mfma(
    const unsigned short* QUh, const unsigned short* QUl,
    const unsigned short* QVh, const unsigned short* QVl,
    int wr, int wc, int fr, int fk, f32x4 acc[4][4])
{
    short8 ah[4], al[4];
#pragma unroll
    for (int i = 0; i < 4; i++) {
        ah[i] = *(const short8*)&QUh[(wr + i * 16 + fr) * 40 + fk];
        al[i] = *(const short8*)&QUl[(wr + i * 16 + fr) * 40 + fk];
    }
#pragma unroll
    for (int j = 0; j < 4; j++) {
        short8 bh = *(const short8*)&QVh[(wc + j * 16 + fr) * 40 + fk];
        short8 bl = *(const short8*)&QVl[(wc + j * 16 + fr) * 40 + fk];
#pragma unroll
        for (int i = 0; i < 4; i++) {
            acc[i][j] = __builtin_amdgcn_mfma_f32_16x16x32_bf16(al[i], bl, acc[i][j], 0, 0, 0);
            acc[i][j] = __builtin_amdgcn_mfma_f32_16x16x32_bf16(al[i], bh, acc[i][j], 0, 0, 0);
            acc[i][j] = __builtin_amdgcn_mfma_f32_16x16x32_bf16(ah[i], bl, acc[i][j], 0, 0, 0);
            acc[i][j] = __builtin_amdgcn_mfma_f32_16x16x32_bf16(ah[i], bh, acc[i][j], 0, 0, 0);
        }
    }
}

// ---------- K0 v10: prep B planes (unchanged) ----------
__global__ __launch_bounds__(256) void v10_prepB(
    const float* __restrict__ u_t, const float* __restrict__ v_t,
    const float* __restrict__ u_c, const float* __restrict__ v_c,
    unsigned int* __restrict__ Bp, unsigned int* __restrict__ Pp)
{
    __shared__ float Ts[64][65];
    const int mtx = blockIdx.y;
    const float* src = (mtx == 0) ? u_t : (mtx == 1) ? v_t : (mtx == 2) ? u_c : v_c;
    unsigned int* dst  = Bp + (size_t)mtx * 65536;
    unsigned int* pdst = Pp + (size_t)mtx * 65536;
    const int k0 = (blockIdx.x >> 2) * 64;
    const int c0 = (blockIdx.x & 3) * 64;
    const int tid = threadIdx.x;
    const int lr = tid >> 2;
    const int lc0 = (tid & 3) * 16;
    float av[16];
#pragma unroll
    for (int q = 0; q < 4; q++) {
        float4 x = *(const float4*)(src + (size_t)(k0 + lr) * 256 + c0 + lc0 + q * 4);
        *(float4*)&av[q * 4] = x;
        *(float4*)&Ts[lr][lc0 + q * 4] = x;
    }
#pragma unroll
    for (int q = 0; q < 4; q++) {
        unsigned int w[4];
#pragma unroll
        for (int e = 0; e < 4; e++) {
            float x = av[q * 4 + e];
            unsigned short hi = f2b(x);
            unsigned short lo = f2b(x - bf2f(hi));
            w[e] = (unsigned int)hi | ((unsigned int)lo << 16);
        }
        *(uint4*)(pdst + (size_t)(k0 + lr) * 256 + c0 + lc0 + q * 4) =
            make_uint4(w[0], w[1], w[2], w[3]);
    }
    __syncthreads();
#pragma unroll
    for (int q = 0; q < 4; q++) {
        unsigned int w[4];
#pragma unroll
        for (int e = 0; e < 4; e++) {
            float x = Ts[lc0 + q * 4 + e][lr];
            unsigned short hi = f2b(x);
            unsigned short lo = f2b(x - bf2f(hi));
            w[e] = (unsigned int)hi | ((unsigned int)lo << 16);
        }
        *(uint4*)(dst + (size_t)(c0 + lr) * 256 + k0 + lc0 + q * 4) =
            make_uint4(w[0], w[1], w[2], w[3]);
    }
}

// ---------- K1 v10: proj via MFMA (unchanged) ----------
__global__ __launch_bounds__(256) void v10_proj(
    const float* __restrict__ qz,
    const unsigned int* __restrict__ Pu, const unsigned int* __restrict__ Pv,
    float* __restrict__ qu_rot, float* __restrict__ qv_rot, int chan, int posmask)
{
    __shared__ __align__(16) unsigned short Ah[128][40];
    __shared__ __align__(16) unsigned short Al[128][40];
    __shared__ __align__(16) unsigned short Bh[128][40];
    __shared__ __align__(16) unsigned short Bl[128][40];
    const int row0 = blockIdx.x * 128;
    const int col0 = blockIdx.y * 128;
    const unsigned int* Bsrc = (col0 < 256) ? Pu : Pv;
    float* Cout = (col0 < 256) ? qu_rot : qv_rot;
    const int ccol0 = col0 & 255;
    const int tid = threadIdx.x;
    const int sr = tid >> 1;
    const int sk = (tid & 1) * 16;
    const int wv = tid >> 6;
    const int lane = tid & 63;
    const int wr = (wv >> 1) * 64, wc = (wv & 1) * 64;
    const int fr = lane & 15;
    const int fk = (lane >> 4) * 8;

    int arow = row0 + sr;
    if (chan) {
        int b = arow >> 12, p = (arow >> 5) & 127, c = arow & 31;
        arow = (b * 32 + c) * 128 + p;
    }
    const float* aptr = qz + (size_t)arow * 256 + sk;
    const unsigned int* bptr = Bsrc + (size_t)(ccol0 + sr) * 256 + sk;

    f32x4 acc[4][4] = {};

    for (int k0 = 0; k0 < 256; k0 += 32) {
        float av[16];
#pragma unroll
        for (int q = 0; q < 4; q++)
            *(float4*)&av[q * 4] = *(const float4*)(aptr + k0 + q * 4);
        unsigned int wh[8], wl[8];
#pragma unroll
        for (int e = 0; e < 8; e++) {
            unsigned short h0 = f2b(av[2 * e]), h1 = f2b(av[2 * e + 1]);
            unsigned short l0 = f2b(av[2 * e] - bf2f(h0));
            unsigned short l1 = f2b(av[2 * e + 1] - bf2f(h1));
            wh[e] = (unsigned int)h0 | ((unsigned int)h1 << 16);
            wl[e] = (unsigned int)l0 | ((unsigned int)l1 << 16);
        }
        *(uint4*)&Ah[sr][sk]     = make_uint4(wh[0], wh[1], wh[2], wh[3]);
        *(uint4*)&Ah[sr][sk + 8] = make_uint4(wh[4], wh[5], wh[6], wh[7]);
        *(uint4*)&Al[sr][sk]     = make_uint4(wl[0], wl[1], wl[2], wl[3]);
        *(uint4*)&Al[sr][sk + 8] = make_uint4(wl[4], wl[5], wl[6], wl[7]);
#pragma unroll
        for (int q = 0; q < 4; q++) {
            uint4 w = *(const uint4*)(bptr + k0 + q * 4);
            *(uint2*)&Bh[sr][sk + q * 4] = make_uint2(
                __builtin_amdgcn_perm(w.y, w.x, PERM_LO),
                __builtin_amdgcn_perm(w.w, w.z, PERM_LO));
            *(uint2*)&Bl[sr][sk + q * 4] = make_uint2(
                __builtin_amdgcn_perm(w.y, w.x, PERM_HI),
                __builtin_amdgcn_perm(w.w, w.z, PERM_HI));
        }
        __syncthreads();
        short8 ah[4], al[4];
#pragma unroll
        for (int i = 0; i < 4; i++) {
            ah[i] = *(const short8*)&Ah[wr + i * 16 + fr][fk];
            al[i] = *(const short8*)&Al[wr + i * 16 + fr][fk];
        }
#pragma unroll
        for (int j = 0; j < 4; j++) {
            const int bc = wc + j * 16 + fr;
            short8 bh = *(const short8*)&Bh[bc][fk];
            short8 bl = *(const short8*)&Bl[bc][fk];
#pragma unroll
            for (int i = 0; i < 4; i++) {
                acc[i][j] = __builtin_amdgcn_mfma_f32_16x16x32_bf16(ah[i], bh, acc[i][j], 0, 0, 0);
                acc[i][j] = __builtin_amdgcn_mfma_f32_16x16x32_bf16(ah[i], bl, acc[i][j], 0, 0, 0);
                acc[i][j] = __builtin_amdgcn_mfma_f32_16x16x32_bf16(al[i], bh, acc[i][j], 0, 0, 0);
                acc[i][j] = __builtin_amdgcn_mfma_f32_16x16x32_bf16(al[i], bl, acc[i][j], 0, 0, 0);
            }
        }
        __syncthreads();
    }
    const float fscale = exp2f(-(float)fr * LOG2T_16);
#pragma unroll
    for (int i = 0; i < 4; i++) {
#pragma unroll
        for (int r = 0; r < 4; r++) {
            int mr = row0 + wr + i * 16 + (lane >> 4) * 4 + r;
            float pos = (float)(mr & posmask);
            float sn, cs;
            sincosf(pos * fscale, &sn, &cs);
            float* op = Cout + (size_t)mr * 256 + ccol0 + wc + fr;
#pragma unroll
            for (int t = 0; t < 2; t++) {
                float x = acc[i][2 * t][r], y = acc[i][2 * t + 1][r];
                op[t * 32]      = x * cs - y * sn;
                op[t * 32 + 16] = y * cs + x * sn;
            }
        }
    }
}

// ---------- K2 v11: time-path stats via MFMA QK^T; XCD co-location ----------
__global__ __launch_bounds__(256) void v11_stats_t(
    const float* __restrict__ quR, const float* __restrict__ qvR,
    const float* __restrict__ mask, float* __restrict__ omax, float* __restrict__ osum)
{
    __shared__ __align__(16) unsigned short QUh[5120];  // [128][40]
    __shared__ __align__(16) unsigned short QUl[5120];
    __shared__ __align__(16) unsigned short QVh[5120];
    __shared__ __align__(16) unsigned short QVl[5120];
    __shared__ float Mp[128][2];
    __shared__ float Sp[128][2];
    const int bid = blockIdx.x;
    const int n = bid & 255, h = bid >> 8;      // same-n blocks -> same XCD
    const int b = n >> 5, c = n & 31;
    const int tid = threadIdx.x;
    const int lane = tid & 63, wv = tid >> 6;
    const int wr = (wv >> 1) * 64, wc = (wv & 1) * 64;
    const int fr = lane & 15, fk = (lane >> 4) * 8;

    qk_stage_splits(quR, qvR, n, h, tid, QUh, QUl, QVh, QVl);
    __syncthreads();
    f32x4 acc[4][4] = {};
    qk_mfma(QUh, QUl, QVh, QVl, wr, wc, fr, fk, acc);
    // vv = 256*(dot + mask) in place
    const float* mbase = mask + (size_t)n * 16384;
#pragma unroll
    for (int i = 0; i < 4; i++)
#pragma unroll
        for (int j = 0; j < 4; j++) {
            int t = wc + j * 16 + fr;
#pragma unroll
            for (int reg = 0; reg < 4; reg++) {
                int s = wr + i * 16 + (lane >> 4) * 4 + reg;
                acc[i][j][reg] = 256.f * (acc[i][j][reg] + mbase[s * 128 + t]);
            }
        }
    // per-wave rowwise partial max/sum over this wave's 64 cols
#pragma unroll
    for (int i = 0; i < 4; i++)
#pragma unroll
        for (int reg = 0; reg < 4; reg++) {
            float m = fmaxf(fmaxf(acc[i][0][reg], acc[i][1][reg]),
                            fmaxf(acc[i][2][reg], acc[i][3][reg]));
            m = fmaxf(m, __shfl_xor(m, 1));
            m = fmaxf(m, __shfl_xor(m, 2));
            m = fmaxf(m, __shfl_xor(m, 4));
            m = fmaxf(m, __shfl_xor(m, 8));
            float sm = __expf(acc[i][0][reg] - m) + __expf(acc[i][1][reg] - m)
                     + __expf(acc[i][2][reg] - m) + __expf(acc[i][3][reg] - m);
            sm += __shfl_xor(sm, 1);
            sm += __shfl_xor(sm, 2);
            sm += __shfl_xor(sm, 4);
            sm += __shfl_xor(sm, 8);
            if (fr == 0) {
                int s = wr + i * 16 + (lane >> 4) * 4 + reg;
                Mp[s][wc >> 6] = m;
                Sp[s][wc >> 6] = sm;
            }
        }
    __syncthreads();
    if (tid < 128) {
        int s = tid;
        float m0 = Mp[s][0], m1 = Mp[s][1];
        float M = fmaxf(m0, m1);
        float S = Sp[s][0] * __expf(m0 - M) + Sp[s][1] * __expf(m1 - M);
        int idx = ((b * 8 + h) * 32 + c) * 128 + s;
        omax[idx] = M; osum[idx] = S;
    }
}

// ---------- K3: chan-path stats (unchanged scalar) ----------
__global__ __launch_bounds__(256) void v5_stats_c(
    const float* __restrict__ quR, const float* __restrict__ qvR,
    const float* __restrict__ mask, float* __restrict__ omax, float* __restrict__ osum)
{
    __shared__ float Qv[32][260];
    const int m = blockIdx.x;
    const int b = m >> 7, p = m & 127;
    const int tid = threadIdx.x;
    for (int idx = tid * 4; idx < 8192; idx += 1024) {
        int sc = idx >> 8, dd = idx & 255;
        *(float4*)&Qv[sc][dd] = *(const float4*)(qvR + ((size_t)m * 32 + sc) * 256 + dd);
    }
    const int h = tid >> 5, sc = tid & 31;
    float qurow[32];
    const float* qptr = quR + ((size_t)m * 32 + sc) * 256 + h * 32;
#pragma unroll
    for (int q = 0; q < 8; q++) {
        float4 x = *(const float4*)(qptr + q * 4);
        qurow[q * 4 + 0] = x.x; qurow[q * 4 + 1] = x.y; qurow[q * 4 + 2] = x.z; qurow[q * 4 + 3] = x.w;
    }
    __syncthreads();
    const float* mrow = mask + (size_t)m * 1024 + sc * 32;
    float mx = -1e30f, sm = 0.f;
#pragma unroll 4
    for (int t = 0; t < 32; t++) {
        float dot = v5_dot32(qurow, &Qv[t][h * 32]);
        float vv = 256.f * (dot + mrow[t]);
        float nm = fmaxf(mx, vv);
        sm = sm * __expf(mx - nm) + __expf(vv - nm);
        mx = nm;
    }
    int idx = ((b * 8 + h) * 32 + sc) * 128 + p;
    omax[idx] = mx; osum[idx] = sm;
}

// ---------- K4: merge (unchanged) ----------
__global__ __launch_bounds__(256) void v5_merge(
    const float* __restrict__ mt, const float* __restrict__ st,
    const float* __restrict__ mc, const float* __restrict__ sc,
    float* __restrict__ Mo, float* __restrict__ So)
{
    int i = blockIdx.x * 256 + threadIdx.x;
    float a = mt[i], b = mc[i];
    float mx = fmaxf(a, b);
    float s = st[i] * __expf(a - mx) + sc[i] * __expf(b - mx);
    Mo[i] = mx;
    So[i] = 1.f / s;
}

// ---------- K5 v11: time-path G; MFMA QK^T + MFMA PV; XCD co-location ----------
__global__ __launch_bounds__(256) void v11_G_t(
    const float* quR, const float* qvR,
    const float* __restrict__ mask, const float* __restrict__ Mr, const float* __restrict__ Sv,
    unsigned short* gpl)
{
    __shared__ __align__(16) unsigned char LB[49152];
    unsigned short* Pm  = (unsigned short*)LB;            // [16384] u16 (32768B)
    unsigned short* QT  = (unsigned short*)(LB + 32768);  // 8192 u16 (hi @0, lo @4096)
    unsigned short* QUh = (unsigned short*)LB;            // [128][40] splits (alias, dead after QK^T)
    unsigned short* QUl = QUh + 5120;
    unsigned short* QVh = QUh + 10240;
    unsigned short* QVl = QUh + 15360;
    const int bid = blockIdx.x;
    const int n = bid & 255, h = bid >> 8;
    const int b = n >> 5, c = n & 31;
    const int tid = threadIdx.x;
    const int lane = tid & 63, wv = tid >> 6;
    const int wr = (wv >> 1) * 64, wc = (wv & 1) * 64;
    const int fr = lane & 15, kgl = lane >> 4;
    const int fk = kgl * 8;

    // phase 0: stage qu/qv hi-lo splits
    qk_stage_splits(quR, qvR, n, h, tid, QUh, QUl, QVh, QVl);
    __syncthreads();
    // phase 1: MFMA QK^T (identical to stats)
    {
        f32x4 acc[4][4] = {};
        qk_mfma(QUh, QUl, QVh, QVl, wr, wc, fr, fk, acc);
        __syncthreads();                         // splits dead; Pm writable
        // phase 1b: P = exp(vv - Mx)*Si -> Pm swizzled
        const float* mbase = mask + (size_t)n * 16384;
        const int rowbase = ((b * 8 + h) * 32 + c) * 128;
#pragma unroll
        for (int i = 0; i < 4; i++) {
            float Mx4[4], Si4[4];
#pragma unroll
            for (int reg = 0; reg < 4; reg++) {
                int s = wr + i * 16 + kgl * 4 + reg;
                Mx4[reg] = Mr[rowbase + s];
                Si4[reg] = Sv[rowbase + s];
            }
#pragma unroll
            for (int j = 0; j < 4; j++) {
                int t = wc + j * 16 + fr;
#pragma unroll
                for (int reg = 0; reg < 4; reg++) {
                    int s = wr + i * 16 + kgl * 4 + reg;
                    float vv = 256.f * (acc[i][j][reg] + mbase[s * 128 + t]);
                    float pv = __expf(vv - Mx4[reg]) * Si4[reg];
                    int ct = (((t >> 3) ^ (s & 15)) << 3) | (t & 7);
                    Pm[s * 128 + ct] = f2b(pv);
                }
            }
        }
    }
    __syncthreads();
    // phase 2: build QvT hi/lo (transposed, swizzled) from GLOBAL qvR
    {
        const int t = tid >> 1, rh = (tid & 1) * 16;
        const float* src = qvR + ((size_t)(n * 128 + t)) * 256 + h * 32 + rh;
        float v[16];
#pragma unroll
        for (int q = 0; q < 4; q++)
            *(float4*)&v[q * 4] = *(const float4*)(src + q * 4);
#pragma unroll
        for (int i = 0; i < 16; i++) {
            int r = rh + i;
            unsigned short hi = f2b(v[i]);
            unsigned short lo = f2b(v[i] - bf2f(hi));
            int ct = (((t >> 3) ^ (r & 15)) << 3) | (t & 7);
            QT[r * 128 + ct] = hi;
            QT[4096 + r * 128 + ct] = lo;
        }
    }
    __syncthreads();
    // phase 3: g1 = P @ Qv (MFMA), rotate (apply_o, pos=s) -> regs
    unsigned int g1h[8];
    {
        f32x4 acc[2][2] = {};
#pragma unroll
        for (int kw = 0; kw < 4; kw++) {
            short8 a[2];
#pragma unroll
            for (int i = 0; i < 2; i++) {
                int row = wv * 32 + i * 16 + fr;
                a[i] = *(const short8*)&Pm[row * 128 + (((kw * 4 + kgl) ^ (row & 15)) << 3)];
            }
            short8 bh[2], bl[2];
#pragma unroll
            for (int j = 0; j < 2; j++) {
                int r = j * 16 + fr;
                int off = r * 128 + (((kw * 4 + kgl) ^ (r & 15)) << 3);
                bh[j] = *(const short8*)&QT[off];
                bl[j] = *(const short8*)&QT[4096 + off];
            }
#pragma unroll
            for (int i = 0; i < 2; i++)
#pragma unroll
                for (int j = 0; j < 2; j++) {
                    acc[i][j] = __builtin_amdgcn_mfma_f32_16x16x32_bf16(a[i], bh[j], acc[i][j], 0, 0, 0);
                    acc[i][j] = __builtin_amdgcn_mfma_f32_16x16x32_bf16(a[i], bl[j], acc[i][j], 0, 0, 0);
                }
        }
#pragma unroll
        for (int i = 0; i < 2; i++)
#pragma unroll
            for (int reg = 0; reg < 4; reg++) {
                int s = wv * 32 + i * 16 + kgl * 4 + reg;
                float ang = (float)s * exp2f(-(float)fr * LOG2T_16);
                float sn, cs;
                __sincosf(ang, &sn, &cs);
                float x = acc[i][0][reg], y = acc[i][1][reg];
                g1h[i * 4 + reg] = (unsigned int)f2b(x * cs + y * sn)
                                 | ((unsigned int)f2b(y * cs - x * sn) << 16);
            }
    }
    __syncthreads();
    // phase 4: build QoT hi/lo = R(-2theta)*quR transposed (LAST quR reads)
    {
        const int t = tid >> 1, jh = (tid & 1) * 8;
        const float* base = quR + ((size_t)(n * 128 + t)) * 256 + h * 32;
        float aa[8], bb[8];
        *(float4*)&aa[0] = *(const float4*)(base + jh);
        *(float4*)&aa[4] = *(const float4*)(base + jh + 4);
        *(float4*)&bb[0] = *(const float4*)(base + jh + 16);
        *(float4*)&bb[4] = *(const float4*)(base + jh + 20);
#pragma unroll
        for (int i = 0; i < 8; i++) {
            int j = jh + i;
            float ang = 2.f * (float)t * exp2f(-(float)j * LOG2T_16);
            float s2, c2;
            __sincosf(ang, &s2, &c2);
            float o1 = aa[i] * c2 + bb[i] * s2;
            float o2 = bb[i] * c2 - aa[i] * s2;
            int ct1 = (((t >> 3) ^ (j & 15)) << 3) | (t & 7);
            unsigned short h1 = f2b(o1);
            QT[j * 128 + ct1] = h1;
            QT[4096 + j * 128 + ct1] = f2b(o1 - bf2f(h1));
            int r2 = j + 16;
            int ct2 = (((t >> 3) ^ (r2 & 15)) << 3) | (t & 7);
            unsigned short h2 = f2b(o2);
            QT[r2 * 128 + ct2] = h2;
            QT[4096 + r2 * 128 + ct2] = f2b(o2 - bf2f(h2));
        }
    }
    __syncthreads();
    // phase 5: g2T = QoT @ P, rotate (apply) -> regs
    unsigned int g2h[8];
    {
        f32x4 acc[2][2] = {};
#pragma unroll
        for (int kw = 0; kw < 4; kw++) {
            short8 ah[2], al[2];
#pragma unroll
            for (int i = 0; i < 2; i++) {
                int r = i * 16 + fr;
                int off = r * 128 + (((kw * 4 + kgl) ^ (r & 15)) << 3);
                ah[i] = *(const short8*)&QT[off];
                al[i] = *(const short8*)&QT[4096 + off];
            }
            short8 bfr[2];
#pragma unroll
            for (int jj = 0; jj < 2; jj++) {
                int scol = (2 * wv + jj) * 16 + fr;
#pragma unroll
                for (int j = 0; j < 8; j++) {
                    int t = kw * 32 + kgl * 8 + j;
                    int ct = (((scol >> 3) ^ (t & 15)) << 3) | (scol & 7);
                    bfr[jj][j] = (short)Pm[t * 128 + ct];
                }
            }
#pragma unroll
            for (int i = 0; i < 2; i++)
#pragma unroll
                for (int jj = 0; jj < 2; jj++) {
                    acc[i][jj] = __builtin_amdgcn_mfma_f32_16x16x32_bf16(ah[i], bfr[jj], acc[i][jj], 0, 0, 0);
                    acc[i][jj] = __builtin_amdgcn_mfma_f32_16x16x32_bf16(al[i], bfr[jj], acc[i][jj], 0, 0, 0);
                }
        }
#pragma unroll
        for (int jj = 0; jj < 2; jj++)
#pragma unroll
            for (int reg = 0; reg < 4; reg++) {
                int sv = (2 * wv + jj) * 16 + fr;
                int r = kgl * 4 + reg;
                float ang = (float)sv * exp2f(-(float)r * LOG2T_16);
                float sn, cs;
                __sincosf(ang, &sn, &cs);
                float x = acc[0][jj][reg], y = acc[1][jj][reg];
                g2h[jj * 4 + reg] = (unsigned int)f2b(x * cs - y * sn)
                                  | ((unsigned int)f2b(y * cs + x * sn) << 16);
            }
    }
    __syncthreads();
    // phase 6: bounce rotated g1/g2 into Pm region
    {
#pragma unroll
        for (int i = 0; i < 2; i++)
#pragma unroll
            for (int reg = 0; reg < 4; reg++) {
                int s = wv * 32 + i * 16 + kgl * 4 + reg;
                unsigned int w = g1h[i * 4 + reg];
                Pm[s * 32 + fr] = (unsigned short)w;
                Pm[s * 32 + fr + 16] = (unsigned short)(w >> 16);
            }
#pragma unroll
        for (int jj = 0; jj < 2; jj++)
#pragma unroll
            for (int reg = 0; reg < 4; reg++) {
                int s = (2 * wv + jj) * 16 + fr;
                int r = kgl * 4 + reg;
                unsigned int w = g2h[jj * 4 + reg];
                Pm[4096 + s * 32 + r] = (unsigned short)w;
                Pm[4096 + s * 32 + r + 16] = (unsigned short)(w >> 16);
            }
    }
    __syncthreads();
    // phase 7: coalesced planar stores
    {
        const int s = tid >> 1, rh = (tid & 1) * 16;
        size_t baseu = ((size_t)(n * 128 + s)) * 512 + h * 64 + rh;
        *(uint4*)(gpl + baseu)      = *(const uint4*)&Pm[s * 32 + rh];
        *(uint4*)(gpl + baseu + 8)  = *(const uint4*)&Pm[s * 32 + rh + 8];
        *(uint4*)(gpl + baseu + 32) = *(const uint4*)&Pm[4096 + s * 32 + rh];
        *(uint4*)(gpl + baseu + 40) = *(const uint4*)&Pm[4096 + s * 32 + rh + 8];
    }
}

// ---------- K6 v8: chan-path G, scalar (unchanged) ----------
__global__ __launch_bounds__(256) void v8_G_c(
    const float* quR, const float* qvR,
    const float* __restrict__ mask, const float* __restrict__ Mr, const float* __restrict__ Sv,
    unsigned short* gpl)
{
    __shared__ float Qv[32][260];
    __shared__ unsigned short Pm[8][32][34];
    const int m = blockIdx.x;
    const int b = m >> 7, p = m & 127;
    const int tid = threadIdx.x;
    for (int idx = tid * 4; idx < 8192; idx += 1024) {
        int sc = idx >> 8, dd = idx & 255;
        *(float4*)&Qv[sc][dd] = *(const float4*)(qvR + ((size_t)m * 32 + sc) * 256 + dd);
    }
    const int h = tid >> 5, sc = tid & 31;
    {
        float qurow[32];
        const float* qptr = quR + ((size_t)m * 32 + sc) * 256 + h * 32;
#pragma unroll
        for (int q = 0; q < 8; q++) {
            float4 x = *(const float4*)(qptr + q * 4);
            qurow[q * 4 + 0] = x.x; qurow[q * 4 + 1] = x.y; qurow[q * 4 + 2] = x.z; qurow[q * 4 + 3] = x.w;
        }
        __syncthreads();
        const int rowidx = ((b * 8 + h) * 32 + sc) * 128 + p;
        const float Mx = Mr[rowidx], Si = Sv[rowidx];
        const float* mrow = mask + (size_t)m * 1024 + sc * 32;
#pragma unroll 4
        for (int t = 0; t < 32; t++) {
            float dot = v5_dot32(qurow, &Qv[t][h * 32]);
            float pv = __expf(256.f * (dot + mrow[t]) - Mx) * Si;
            Pm[h][t][sc] = f2b(pv);
        }
    }
    __syncthreads();
    float a[32] = {};
#pragma unroll 4
    for (int t = 0; t < 32; t++) {
        float p_ = bf2f(Pm[h][t][sc]);
        v5_fma32(p_, &Qv[t][h * 32], a);
    }
    float cs[16], sn[16];
#pragma unroll
    for (int i = 0; i < 16; i++) {
        float ang = (float)sc * exp2f(-(float)i * LOG2T_16);
        __sincosf(ang, &sn[i], &cs[i]);
    }
    unsigned int g1p[8], g1q[8];
#pragma unroll
    for (int j = 0; j < 8; j++) {
        int i0 = 2 * j, i1 = 2 * j + 1;
        float x0 = a[i0], y0 = a[16 + i0], x1 = a[i1], y1 = a[16 + i1];
        g1p[j] = (unsigned int)f2b(x0 * cs[i0] + y0 * sn[i0])
               | ((unsigned int)f2b(x1 * cs[i1] + y1 * sn[i1]) << 16);
        g1q[j] = (unsigned int)f2b(y0 * cs[i0] - x0 * sn[i0])
               | ((unsigned int)f2b(y1 * cs[i1] - x1 * sn[i1]) << 16);
    }
    __syncthreads();
    for (int idx = tid * 4; idx < 4096; idx += 1024) {
        int row = idx >> 7, rem = idx & 127;
        int h2 = rem >> 4, j0 = rem & 15;
        const float* base = quR + ((size_t)m * 32 + row) * 256 + h2 * 32;
        float4 a4 = *(const float4*)(base + j0);
        float4 b4 = *(const float4*)(base + j0 + 16);
        float aa[4] = {a4.x, a4.y, a4.z, a4.w};
        float bb[4] = {b4.x, b4.y, b4.z, b4.w};
        float o1[4], o2[4];
#pragma unroll
        for (int i = 0; i < 4; i++) {
            float ang = 2.f * (float)row * exp2f(-(float)(j0 + i) * LOG2T_16);
            float s2, c2;
            __sincosf(ang, &s2, &c2);
            o1[i] = aa[i] * c2 + bb[i] * s2;
            o2[i] = bb[i] * c2 - aa[i] * s2;
        }
        *(float4*)&Qv[row][h2 * 32 + j0]      = make_float4(o1[0], o1[1], o1[2], o1[3]);
        *(float4*)&Qv[row][h2 * 32 + j0 + 16] = make_float4(o2[0], o2[1], o2[2], o2[3]);
    }
    __syncthreads();
#pragma unroll
    for (int i = 0; i < 32; i++) a[i] = 0.f;
#pragma unroll 4
    for (int t = 0; t < 32; t++) {
        float p_ = bf2f(Pm[h][sc][t]);
        v5_fma32(p_, &Qv[t][h * 32], a);
    }
    unsigned int* gpu = (unsigned int*)gpl;
    size_t ub = ((size_t)m * 32 + sc) * 256 + h * 32;
    *(uint4*)(gpu + ub)      = make_uint4(g1p[0], g1p[1], g1p[2], g1p[3]);
    *(uint4*)(gpu + ub + 4)  = make_uint4(g1p[4], g1p[5], g1p[6], g1p[7]);
    *(uint4*)(gpu + ub + 8)  = make_uint4(g1q[0], g1q[1], g1q[2], g1q[3]);
    *(uint4*)(gpu + ub + 12) = make_uint4(g1q[4], g1q[5], g1q[6], g1q[7]);
    unsigned int p2[8], q2[8];
#pragma unroll
    for (int j = 0; j < 8; j++) {
        int i0 = 2 * j, i1 = 2 * j + 1;
        p2[j] = (unsigned int)f2b(a[i0] * cs[i0] - a[16 + i0] * sn[i0])
              | ((unsigned int)f2b(a[i1] * cs[i1] - a[16 + i1] * sn[i1]) << 16);
        q2[j] = (unsigned int)f2b(a[16 + i0] * cs[i0] + a[i0] * sn[i0])
              | ((unsigned int)f2b(a[16 + i1] * cs[i1] + a[i1] * sn[i1]) << 16);
    }
    *(uint4*)(gpu + ub + 16) = make_uint4(p2[0], p2[1], p2[2], p2[3]);
    *(uint4*)(gpu + ub + 20) = make_uint4(p2[4], p2[5], p2[6], p2[7]);
    *(uint4*)(gpu + ub + 24) = make_uint4(q2[0], q2[1], q2[2], q2[3]);
    *(uint4*)(gpu + ub + 28) = make_uint4(q2[4], q2[5], q2[6], q2[7]);
}

// ---------- K7 v8: outgemm (unchanged) ----------
__global__ __launch_bounds__(256) void v8_outgemm(
    const unsigned short* __restrict__ gpl,
    const unsigned int* __restrict__ Bu,
    const unsigned int* __restrict__ Bv,
    float* __restrict__ out, int remap)
{
    __shared__ __align__(16) unsigned short A1[128][40];
    __shared__ __align__(16) unsigned short A2[128][40];
    __shared__ __align__(16) unsigned short Bh[2][128][40];
    __shared__ __align__(16) unsigned short Bl[2][128][40];
    const int row0 = blockIdx.x * 128;
    const int col0 = blockIdx.y * 128;
    const int tid = threadIdx.x;
    const int sr = tid >> 1;
    const int sk = (tid & 1) * 16;
    const int wv = tid >> 6;
    const int lane = tid & 63;
    const int wr = (wv >> 1) * 64, wc = (wv & 1) * 64;
    const int fr = lane & 15;
    const int fk = (lane >> 4) * 8;

    const unsigned int* uptr = Bu + (size_t)(col0 + sr) * 256 + sk;
    const unsigned int* vptr = Bv + (size_t)(col0 + sr) * 256 + sk;

    f32x4 acc[4][4] = {};

    for (int k0 = 0; k0 < 256; k0 += 32) {
        int kb = k0 + sk;
        const unsigned short* ap = gpl + (size_t)(row0 + sr) * 512 + ((kb >> 5) << 6) + (kb & 31);
        *(uint4*)&A1[sr][sk]     = *(const uint4*)ap;
        *(uint4*)&A1[sr][sk + 8] = *(const uint4*)(ap + 8);
        *(uint4*)&A2[sr][sk]     = *(const uint4*)(ap + 32);
        *(uint4*)&A2[sr][sk + 8] = *(const uint4*)(ap + 40);
#pragma unroll
        for (int q = 0; q < 4; q++) {
            uint4 wU = *(const uint4*)(uptr + k0 + q * 4);
            *(uint2*)&Bh[0][sr][sk + q * 4] = make_uint2(
                __builtin_amdgcn_perm(wU.y, wU.x, PERM_LO),
                __builtin_amdgcn_perm(wU.w, wU.z, PERM_LO));
            *(uint2*)&Bl[0][sr][sk + q * 4] = make_uint2(
                __builtin_amdgcn_perm(wU.y, wU.x, PERM_HI),
                __builtin_amdgcn_perm(wU.w, wU.z, PERM_HI));
            uint4 wV = *(const uint4*)(vptr + k0 + q * 4);
            *(uint2*)&Bh[1][sr][sk + q * 4] = make_uint2(
                __builtin_amdgcn_perm(wV.y, wV.x, PERM_LO),
                __builtin_amdgcn_perm(wV.w, wV.z, PERM_LO));
            *(uint2*)&Bl[1][sr][sk + q * 4] = make_uint2(
                __builtin_amdgcn_perm(wV.y, wV.x, PERM_HI),
                __builtin_amdgcn_perm(wV.w, wV.z, PERM_HI));
        }
        __syncthreads();
        short8 a1[4], a2[4];
#pragma unroll
        for (int i = 0; i < 4; i++) {
            a1[i] = *(const short8*)&A1[wr + i * 16 + fr][fk];
            a2[i] = *(const short8*)&A2[wr + i * 16 + fr][fk];
        }
#pragma unroll
        for (int j = 0; j < 4; j++) {
            const int bc = wc + j * 16 + fr;
            short8 buh = *(const short8*)&Bh[0][bc][fk];
            short8 bul = *(const short8*)&Bl[0][bc][fk];
            short8 bvh = *(const short8*)&Bh[1][bc][fk];
            short8 bvl = *(const short8*)&Bl[1][bc][fk];
#pragma unroll
            for (int i = 0; i < 4; i++) {
                acc[i][j] = __builtin_amdgcn_mfma_f32_16x16x32_bf16(a1[i], buh, acc[i][j], 0, 0, 0);
                acc[i][j] = __builtin_amdgcn_mfma_f32_16x16x32_bf16(a1[i], bul, acc[i][j], 0, 0, 0);
                acc[i][j] = __builtin_amdgcn_mfma_f32_16x16x32_bf16(a2[i], bvh, acc[i][j], 0, 0, 0);
                acc[i][j] = __builtin_amdgcn_mfma_f32_16x16x32_bf16(a2[i], bvl, acc[i][j], 0, 0, 0);
            }
        }
        __syncthreads();
    }
#pragma unroll
    for (int i = 0; i < 4; i++) {
#pragma unroll
        for (int r = 0; r < 4; r++) {
            int mr = row0 + wr + i * 16 + (lane >> 4) * 4 + r;
            int orow = mr;
            if (remap) {
                int bb = mr >> 12, pp = (mr >> 5) & 127, cc = mr & 31;
                orow = (bb << 12) + (cc << 7) + pp;
            }
            float* op = out + (size_t)orow * 256 + col0 + wc + fr;
#pragma unroll
            for (int j = 0; j < 4; j++)
                op[j * 16] = acc[i][j][r];
        }
    }
}

extern "C" void kernel_launch(void* const* d_in, const int* in_sizes, int n_in,
                              void* d_out, int out_size, void* d_ws, size_t ws_size,
                              hipStream_t stream)
{
    (void)in_sizes; (void)n_in; (void)out_size; (void)ws_size;
    const float* qz     = (const float*)d_in[0];
    const float* mask_t = (const float*)d_in[1];
    const float* mask_c = (const float*)d_in[2];
    const float* u_time = (const float*)d_in[3];
    const float* v_time = (const float*)d_in[4];
    const float* u_chan = (const float*)d_in[5];
    const float* v_chan = (const float*)d_in[6];
    float* out = (float*)d_out;
    float* W = (float*)d_ws;

    float* quR_t = W;
    float* qvR_t = W + 8388608;
    float* quR_c = W + 16777216;
    float* qvR_c = W + 25165824;
    float* S     = W + 33554432;
    float* max_t = S;
    float* sum_t = S + 262144;
    float* max_c = S + 524288;
    float* sum_c = S + 786432;
    float* Mrow  = S + 1048576;
    float* Sinv  = S + 1310720;
    unsigned int* BP = (unsigned int*)(W + 35127296);   // transposed packed (4 x 65536)
    unsigned int* PP = BP + 262144;                     // natural packed (4 x 65536)
    unsigned short* GPt = (unsigned short*)quR_t;
    unsigned short* GPc = (unsigned short*)quR_c;

    dim3 blk(256);
    v10_prepB<<<dim3(16, 4), blk, 0, stream>>>(u_time, v_time, u_chan, v_chan, BP, PP);
    v10_proj<<<dim3(256, 4), blk, 0, stream>>>(qz, PP, PP + 65536, quR_t, qvR_t, 0, 127);
    v10_proj<<<dim3(256, 4), blk, 0, stream>>>(qz, PP + 131072, PP + 196608, quR_c, qvR_c, 1, 31);
    v11_stats_t<<<2048, blk, 0, stream>>>(quR_t, qvR_t, mask_t, max_t, sum_t);
    v5_stats_c<<<1024, blk, 0, stream>>>(quR_c, qvR_c, mask_c, max_c, sum_c);
    v5_merge<<<1024, blk, 0, stream>>>(max_t, sum_t, max_c, sum_c, Mrow, Sinv);
    v11_G_t<<<2048, blk, 0, stream>>>(quR_t, qvR_t, mask_t, Mrow, Sinv, GPt);
    v8_outgemm<<<dim3(256, 2), blk, 0, stream>>>(GPt, BP, BP + 65536, out, 0);
    v8_G_c<<<1024, blk, 0, stream>>>(quR_c, qvR_c, mask_c, Mrow, Sinv, GPc);
    v8_outgemm<<<dim3(256, 2), blk, 0, stream>>>(GPc, BP + 131072, BP + 196608, out + 8388608, 1);
}